// Round 1
// baseline (9890.508 us; speedup 1.0000x reference)
//
#include <hip/hip_runtime.h>

#define NA 100000
#define NB 100000
#define NEDGE 1600000
#define HD 128
#define OUTD 16
#define NG 256
#define DA 64
#define DB 32

// ---------------- input embedding: h = x @ W + b  (K -> 128) ----------------
template<int K>
__global__ void __launch_bounds__(256)
emb_kernel(const float* __restrict__ x, const float* __restrict__ W,
           const float* __restrict__ bias, float* __restrict__ h, int n)
{
    __shared__ float Ws[K * HD];
    __shared__ float bs[HD];
    for (int i = threadIdx.x; i < K * HD; i += 256) Ws[i] = W[i];
    if (threadIdx.x < HD) bs[threadIdx.x] = bias[threadIdx.x];
    __syncthreads();
    const int wid = threadIdx.x >> 6, lane = threadIdx.x & 63;
    for (int row = blockIdx.x * 4 + wid; row < n; row += gridDim.x * 4) {
        const float* xr = x + (size_t)row * K;
        float a0 = bs[lane], a1 = bs[lane + 64];
#pragma unroll 8
        for (int k = 0; k < K; ++k) {
            const float xv = xr[k];
            a0 = fmaf(xv, Ws[k * HD + lane], a0);
            a1 = fmaf(xv, Ws[k * HD + lane + 64], a1);
        }
        float* hr = h + (size_t)row * HD;
        hr[lane] = a0;
        hr[lane + 64] = a1;
    }
}

// ---------------- edge scatter: s[dst] += hsrc[src], cnt[dst] += 1 ----------------
__global__ void __launch_bounds__(256)
scatter_kernel(const float* __restrict__ hsrc, const int* __restrict__ ei,
               float* __restrict__ s, float* __restrict__ cnt)
{
    const int grp = threadIdx.x >> 5, l = threadIdx.x & 31;
    for (long e = (long)blockIdx.x * 8 + grp; e < NEDGE; e += (long)gridDim.x * 8) {
        const int src = ei[e];
        const int dst = ei[NEDGE + e];
        const float4 v = *reinterpret_cast<const float4*>(hsrc + (size_t)src * HD + l * 4);
        float* sd = s + (size_t)dst * HD + l * 4;
        unsafeAtomicAdd(sd + 0, v.x);
        unsafeAtomicAdd(sd + 1, v.y);
        unsafeAtomicAdd(sd + 2, v.z);
        unsafeAtomicAdd(sd + 3, v.w);
        if (l == 0) unsafeAtomicAdd(cnt + dst, 1.0f);
    }
}

// ---------------- Wsum = Wr_ba + Wr_aa ----------------
__global__ void wsum_kernel(const float* __restrict__ A, const float* __restrict__ B,
                            float* __restrict__ C)
{
    int i = blockIdx.x * blockDim.x + threadIdx.x;
    if (i < HD * HD) C[i] = A[i] + B[i];
}

// ---------------- per-graph node counts ----------------
__global__ void gcnt_kernel(const int* __restrict__ batch, float* __restrict__ gcnt, int n)
{
    int i = blockIdx.x * blockDim.x + threadIdx.x;
    if (i < n) unsafeAtomicAdd(gcnt + batch[i], 1.0f);
}

// ---------------- dst 'b': m = (s/cnt)@Wl + h_b@Wr + bl ; relu ; pool ----------------
__global__ void __launch_bounds__(256)
fused_b_kernel(const float* __restrict__ s, const float* __restrict__ cnt,
               const float* __restrict__ hb,
               const float* __restrict__ Wl, const float* __restrict__ bl,
               const float* __restrict__ Wr, const int* __restrict__ batch,
               float* __restrict__ pool)
{
    extern __shared__ float lds[];
    float* wl = lds;             // 16384
    float* wr = lds + 16384;     // 16384
    float* bs = lds + 32768;     // 128
    for (int i = threadIdx.x; i < 16384; i += 256) { wl[i] = Wl[i]; wr[i] = Wr[i]; }
    if (threadIdx.x < HD) bs[threadIdx.x] = bl[threadIdx.x];
    __syncthreads();
    const int wid = threadIdx.x >> 6, lane = threadIdx.x & 63;
    const int wg = blockIdx.x * 4 + wid, nw = gridDim.x * 4;
    for (int n0 = wg * 2; n0 < NB; n0 += nw * 2) {
        const int n1 = min(n0 + 1, NB - 1);
        const float* s0 = s + (size_t)n0 * HD;
        const float* s1 = s + (size_t)n1 * HD;
        const float* h0 = hb + (size_t)n0 * HD;
        const float* h1 = hb + (size_t)n1 * HD;
        const float i0 = 1.0f / fmaxf(cnt[n0], 1.0f);
        const float i1 = 1.0f / fmaxf(cnt[n1], 1.0f);
        float a00 = bs[lane], a01 = bs[lane + 64];
        float a10 = a00, a11 = a01;
#pragma unroll 4
        for (int k = 0; k < HD; ++k) {
            const float wa0 = wl[k * HD + lane], wa1 = wl[k * HD + lane + 64];
            const float wb0 = wr[k * HD + lane], wb1 = wr[k * HD + lane + 64];
            const float x0 = s0[k] * i0, x1 = s1[k] * i1;
            const float y0 = h0[k],      y1 = h1[k];
            a00 += x0 * wa0 + y0 * wb0;
            a01 += x0 * wa1 + y0 * wb1;
            a10 += x1 * wa0 + y1 * wb0;
            a11 += x1 * wa1 + y1 * wb1;
        }
        const int g0 = batch[n0];
        unsafeAtomicAdd(pool + g0 * HD + lane,      fmaxf(a00, 0.f));
        unsafeAtomicAdd(pool + g0 * HD + lane + 64, fmaxf(a01, 0.f));
        if (n1 > n0) {
            const int g1 = batch[n1];
            unsafeAtomicAdd(pool + g1 * HD + lane,      fmaxf(a10, 0.f));
            unsafeAtomicAdd(pool + g1 * HD + lane + 64, fmaxf(a11, 0.f));
        }
    }
}

// ---------------- dst 'a' pass A: t = (s_ba/cnt)@Wl_ba + (s_aa/cnt)@Wl_aa + (bl_ba+bl_aa)
// written in-place into s_ba (rows are wave-exclusive, read fully before write)
__global__ void __launch_bounds__(256)
passA_kernel(float* s_ba, const float* __restrict__ cnt_ba,
             const float* __restrict__ s_aa, const float* __restrict__ cnt_aa,
             const float* __restrict__ Wl1, const float* __restrict__ bl1,
             const float* __restrict__ Wl2, const float* __restrict__ bl2)
{
    extern __shared__ float lds[];
    float* w1 = lds;
    float* w2 = lds + 16384;
    float* bs = lds + 32768;
    for (int i = threadIdx.x; i < 16384; i += 256) { w1[i] = Wl1[i]; w2[i] = Wl2[i]; }
    if (threadIdx.x < HD) bs[threadIdx.x] = bl1[threadIdx.x] + bl2[threadIdx.x];
    __syncthreads();
    const int wid = threadIdx.x >> 6, lane = threadIdx.x & 63;
    const int wg = blockIdx.x * 4 + wid, nw = gridDim.x * 4;
    for (int n0 = wg * 2; n0 < NA; n0 += nw * 2) {
        const int n1 = min(n0 + 1, NA - 1);
        float* t0 = s_ba + (size_t)n0 * HD;
        float* t1 = s_ba + (size_t)n1 * HD;
        const float* u0 = s_aa + (size_t)n0 * HD;
        const float* u1 = s_aa + (size_t)n1 * HD;
        const float i0a = 1.0f / fmaxf(cnt_ba[n0], 1.0f);
        const float i1a = 1.0f / fmaxf(cnt_ba[n1], 1.0f);
        const float i0b = 1.0f / fmaxf(cnt_aa[n0], 1.0f);
        const float i1b = 1.0f / fmaxf(cnt_aa[n1], 1.0f);
        float a00 = bs[lane], a01 = bs[lane + 64];
        float a10 = a00, a11 = a01;
#pragma unroll 4
        for (int k = 0; k < HD; ++k) {
            const float wa0 = w1[k * HD + lane], wa1 = w1[k * HD + lane + 64];
            const float wb0 = w2[k * HD + lane], wb1 = w2[k * HD + lane + 64];
            const float x0 = t0[k] * i0a, x1 = t1[k] * i1a;
            const float y0 = u0[k] * i0b, y1 = u1[k] * i1b;
            a00 += x0 * wa0 + y0 * wb0;
            a01 += x0 * wa1 + y0 * wb1;
            a10 += x1 * wa0 + y1 * wb0;
            a11 += x1 * wa1 + y1 * wb1;
        }
        t0[lane] = a00; t0[lane + 64] = a01;
        if (n1 > n0) { t1[lane] = a10; t1[lane + 64] = a11; }
    }
}

// ---------------- dst 'a' pass B: m = 0.5*(t + h_a@Wsum) ; relu ; pool ----------------
__global__ void __launch_bounds__(256)
passB_kernel(const float* __restrict__ t, const float* __restrict__ ha,
             const float* __restrict__ Wsum, const int* __restrict__ batch,
             float* __restrict__ pool)
{
    extern __shared__ float lds[];
    float* w = lds; // 16384
    for (int i = threadIdx.x; i < 16384; i += 256) w[i] = Wsum[i];
    __syncthreads();
    const int wid = threadIdx.x >> 6, lane = threadIdx.x & 63;
    const int wg = blockIdx.x * 4 + wid, nw = gridDim.x * 4;
    for (int n0 = wg * 2; n0 < NA; n0 += nw * 2) {
        const int n1 = min(n0 + 1, NA - 1);
        const float* h0 = ha + (size_t)n0 * HD;
        const float* h1 = ha + (size_t)n1 * HD;
        float a00 = 0.f, a01 = 0.f, a10 = 0.f, a11 = 0.f;
#pragma unroll 4
        for (int k = 0; k < HD; ++k) {
            const float w0 = w[k * HD + lane], w1v = w[k * HD + lane + 64];
            const float x0 = h0[k], x1 = h1[k];
            a00 = fmaf(x0, w0, a00); a01 = fmaf(x0, w1v, a01);
            a10 = fmaf(x1, w0, a10); a11 = fmaf(x1, w1v, a11);
        }
        const float m00 = fmaxf(0.5f * (t[(size_t)n0 * HD + lane]      + a00), 0.f);
        const float m01 = fmaxf(0.5f * (t[(size_t)n0 * HD + lane + 64] + a01), 0.f);
        const int g0 = batch[n0];
        unsafeAtomicAdd(pool + g0 * HD + lane,      m00);
        unsafeAtomicAdd(pool + g0 * HD + lane + 64, m01);
        if (n1 > n0) {
            const float m10 = fmaxf(0.5f * (t[(size_t)n1 * HD + lane]      + a10), 0.f);
            const float m11 = fmaxf(0.5f * (t[(size_t)n1 * HD + lane + 64] + a11), 0.f);
            const int g1 = batch[n1];
            unsafeAtomicAdd(pool + g1 * HD + lane,      m10);
            unsafeAtomicAdd(pool + g1 * HD + lane + 64, m11);
        }
    }
}

// ---------------- head: out = (0.5*(pa/ga + pb/gb)) @ Wout + bout ----------------
__global__ void final_kernel(const float* __restrict__ pa, const float* __restrict__ pb,
                             const float* __restrict__ ga, const float* __restrict__ gb,
                             const float* __restrict__ Wout, const float* __restrict__ bout,
                             float* __restrict__ out)
{
    const int g = blockIdx.x;
    const int lane = threadIdx.x;
    const float inva = 1.0f / fmaxf(ga[g], 1.0f);
    const float invb = 1.0f / fmaxf(gb[g], 1.0f);
    if (lane < OUTD) {
        float acc = bout[lane];
        for (int k = 0; k < HD; ++k) {
            const float x = 0.5f * (pa[g * HD + k] * inva + pb[g * HD + k] * invb);
            acc = fmaf(x, Wout[k * OUTD + lane], acc);
        }
        out[g * OUTD + lane] = acc;
    }
}

extern "C" void kernel_launch(void* const* d_in, const int* in_sizes, int n_in,
                              void* d_out, int out_size, void* d_ws, size_t ws_size,
                              hipStream_t stream)
{
    const float* x_a    = (const float*)d_in[0];
    const float* x_b    = (const float*)d_in[1];
    const int*   ei_ab  = (const int*)d_in[2];
    const int*   ei_ba  = (const int*)d_in[3];
    const int*   ei_aa  = (const int*)d_in[4];
    const int*   batch_a = (const int*)d_in[5];
    const int*   batch_b = (const int*)d_in[6];
    const float* Wemb_a = (const float*)d_in[7];
    const float* bemb_a = (const float*)d_in[8];
    const float* Wemb_b = (const float*)d_in[9];
    const float* bemb_b = (const float*)d_in[10];
    const float* Wl_ab  = (const float*)d_in[11];
    const float* bl_ab  = (const float*)d_in[12];
    const float* Wr_ab  = (const float*)d_in[13];
    const float* Wl_ba  = (const float*)d_in[14];
    const float* bl_ba  = (const float*)d_in[15];
    const float* Wr_ba  = (const float*)d_in[16];
    const float* Wl_aa  = (const float*)d_in[17];
    const float* bl_aa  = (const float*)d_in[18];
    const float* Wr_aa  = (const float*)d_in[19];
    const float* Wout   = (const float*)d_in[20];
    const float* bout   = (const float*)d_in[21];
    float* out = (float*)d_out;

    // workspace layout (fp32)
    float* h_a    = (float*)d_ws;                    // NA*HD
    float* h_b    = h_a    + (size_t)NA * HD;        // NB*HD
    float* s_ab   = h_b    + (size_t)NB * HD;        // NB*HD  (dst b)
    float* s_ba   = s_ab   + (size_t)NB * HD;        // NA*HD  (dst a) -> reused as t
    float* s_aa   = s_ba   + (size_t)NA * HD;        // NA*HD  (dst a)
    float* cnt_ab = s_aa   + (size_t)NA * HD;        // NB
    float* cnt_ba = cnt_ab + NB;                     // NA
    float* cnt_aa = cnt_ba + NA;                     // NA
    float* pool_a = cnt_aa + NA;                     // NG*HD
    float* pool_b = pool_a + NG * HD;                // NG*HD
    float* gcnt_a = pool_b + NG * HD;                // NG
    float* gcnt_b = gcnt_a + NG;                     // NG
    float* wsum   = gcnt_b + NG;                     // HD*HD

    // zero all accumulation buffers in one shot (s_ab .. gcnt_b are contiguous)
    const size_t zero_bytes = (size_t)((char*)(gcnt_b + NG) - (char*)s_ab);
    hipMemsetAsync(s_ab, 0, zero_bytes, stream);

    wsum_kernel<<<(HD * HD + 255) / 256, 256, 0, stream>>>(Wr_ba, Wr_aa, wsum);

    emb_kernel<DA><<<(NA + 3) / 4, 256, 0, stream>>>(x_a, Wemb_a, bemb_a, h_a, NA);
    emb_kernel<DB><<<(NB + 3) / 4, 256, 0, stream>>>(x_b, Wemb_b, bemb_b, h_b, NB);

    scatter_kernel<<<(NEDGE + 7) / 8, 256, 0, stream>>>(h_a, ei_ab, s_ab, cnt_ab);
    scatter_kernel<<<(NEDGE + 7) / 8, 256, 0, stream>>>(h_b, ei_ba, s_ba, cnt_ba);
    scatter_kernel<<<(NEDGE + 7) / 8, 256, 0, stream>>>(h_a, ei_aa, s_aa, cnt_aa);

    gcnt_kernel<<<(NA + 255) / 256, 256, 0, stream>>>(batch_a, gcnt_a, NA);
    gcnt_kernel<<<(NB + 255) / 256, 256, 0, stream>>>(batch_b, gcnt_b, NB);

    const int lds_big   = (16384 * 2 + 128) * 4;   // 131584 B
    const int lds_small = 16384 * 4;               // 65536 B
    hipFuncSetAttribute((const void*)fused_b_kernel, hipFuncAttributeMaxDynamicSharedMemorySize, lds_big);
    hipFuncSetAttribute((const void*)passA_kernel,   hipFuncAttributeMaxDynamicSharedMemorySize, lds_big);
    hipFuncSetAttribute((const void*)passB_kernel,   hipFuncAttributeMaxDynamicSharedMemorySize, lds_small);

    fused_b_kernel<<<256, 256, lds_big, stream>>>(s_ab, cnt_ab, h_b, Wl_ab, bl_ab, Wr_ab, batch_b, pool_b);
    passA_kernel  <<<256, 256, lds_big, stream>>>(s_ba, cnt_ba, s_aa, cnt_aa, Wl_ba, bl_ba, Wl_aa, bl_aa);
    passB_kernel  <<<512, 256, lds_small, stream>>>(s_ba, h_a, wsum, batch_a, pool_a);

    final_kernel<<<NG, 64, 0, stream>>>(pool_a, pool_b, gcnt_a, gcnt_b, Wout, bout, out);
}

// Round 2
// 2114.916 us; speedup vs baseline: 4.6765x; 4.6765x over previous
//
#include <hip/hip_runtime.h>

#define NA 100000
#define NB 100000
#define NEDGE 1600000
#define HD 128
#define OUTD 16
#define NG 256
#define DA 64
#define DB 32
#define SCAN_ITEMS 1024

typedef unsigned int uint_t;
typedef unsigned short ushort_t;

__device__ __forceinline__ float bflo(uint_t u) {
    union { uint_t i; float f; } c; c.i = u << 16; return c.f;
}
__device__ __forceinline__ float bfhi(uint_t u) {
    union { uint_t i; float f; } c; c.i = u & 0xffff0000u; return c.f;
}
__device__ __forceinline__ uint_t f2bf(float f) {
    union { float f; uint_t i; } c; c.f = f;
    uint_t r = c.i + 0x7FFFu + ((c.i >> 16) & 1u);
    return r >> 16;
}
__device__ __forceinline__ uint_t pack2bf(float lo, float hi) {
    return f2bf(lo) | (f2bf(hi) << 16);
}

// ---------------- input embedding: h = x @ W + b  (K -> 128), bf16 out ----------------
template<int K>
__global__ void __launch_bounds__(256)
emb_kernel(const float* __restrict__ x, const float* __restrict__ W,
           const float* __restrict__ bias, ushort_t* __restrict__ h, int n)
{
    __shared__ float Ws[K * HD];
    __shared__ float bs[HD];
    for (int i = threadIdx.x; i < K * HD; i += 256) Ws[i] = W[i];
    if (threadIdx.x < HD) bs[threadIdx.x] = bias[threadIdx.x];
    __syncthreads();
    const int wid = threadIdx.x >> 6, lane = threadIdx.x & 63;
    const int c0 = 2 * lane;
    for (int row = blockIdx.x * 4 + wid; row < n; row += gridDim.x * 4) {
        const float* xr = x + (size_t)row * K;
        float a0 = bs[c0], a1 = bs[c0 + 1];
#pragma unroll 8
        for (int k = 0; k < K; ++k) {
            const float xv = xr[k];
            const float2 w = *reinterpret_cast<const float2*>(Ws + k * HD + c0);
            a0 = fmaf(xv, w.x, a0);
            a1 = fmaf(xv, w.y, a1);
        }
        *reinterpret_cast<uint_t*>(h + (size_t)row * HD + c0) = pack2bf(a0, a1);
    }
}

// ---------------- CSR build ----------------
__global__ void __launch_bounds__(256)
deg_kernel(const int* __restrict__ ei, int* __restrict__ deg)
{
    const int e = blockIdx.x * 256 + threadIdx.x;
    if (e < NEDGE) atomicAdd(&deg[ei[NEDGE + e]], 1);
}

__global__ void __launch_bounds__(256)
scan1_kernel(const int* __restrict__ deg, int* __restrict__ bsum, int n)
{
    __shared__ int red[256];
    const int base = blockIdx.x * SCAN_ITEMS + threadIdx.x * 4;
    int s = 0;
#pragma unroll
    for (int j = 0; j < 4; ++j) { const int i = base + j; if (i < n) s += deg[i]; }
    red[threadIdx.x] = s; __syncthreads();
    for (int d = 128; d > 0; d >>= 1) {
        if (threadIdx.x < d) red[threadIdx.x] += red[threadIdx.x + d];
        __syncthreads();
    }
    if (threadIdx.x == 0) bsum[blockIdx.x] = red[0];
}

__global__ void __launch_bounds__(128)
scan2_kernel(const int* __restrict__ bsum, int* __restrict__ bscan, int nblk, int* __restrict__ off_last)
{
    __shared__ int sc[128];
    const int t = threadIdx.x;
    const int v = (t < nblk) ? bsum[t] : 0;
    sc[t] = v; __syncthreads();
    for (int d = 1; d < 128; d <<= 1) {
        const int x = (t >= d) ? sc[t - d] : 0;
        __syncthreads();
        sc[t] += x;
        __syncthreads();
    }
    if (t < nblk) bscan[t] = sc[t] - v;          // exclusive
    if (t == nblk - 1) *off_last = sc[t];        // total = E
}

__global__ void __launch_bounds__(256)
scan3_kernel(const int* __restrict__ deg, const int* __restrict__ bscan,
             int* __restrict__ off, int* __restrict__ cur, int n)
{
    __shared__ int red[256];
    const int t = threadIdx.x;
    const int base = blockIdx.x * SCAN_ITEMS + t * 4;
    int v[4]; int s = 0;
#pragma unroll
    for (int j = 0; j < 4; ++j) { const int i = base + j; v[j] = (i < n) ? deg[i] : 0; s += v[j]; }
    red[t] = s; __syncthreads();
    for (int d = 1; d < 256; d <<= 1) {
        const int x = (t >= d) ? red[t - d] : 0;
        __syncthreads();
        red[t] += x;
        __syncthreads();
    }
    int ex = red[t] - s + bscan[blockIdx.x];
#pragma unroll
    for (int j = 0; j < 4; ++j) {
        const int i = base + j;
        if (i < n) { off[i] = ex; cur[i] = ex; }
        ex += v[j];
    }
}

__global__ void __launch_bounds__(256)
fill_kernel(const int* __restrict__ ei, int* __restrict__ cur, int* __restrict__ csr)
{
    const int e = blockIdx.x * 256 + threadIdx.x;
    if (e >= NEDGE) return;
    const int dst = ei[NEDGE + e];
    const int pos = atomicAdd(&cur[dst], 1);
    csr[pos] = ei[e];
}

// ---------------- gather-aggregate: s[n] = mean over edges of h[src], bf16 ----------------
__global__ void __launch_bounds__(256)
gather_kernel(const ushort_t* __restrict__ hsrc, const int* __restrict__ csr,
              const int* __restrict__ off, ushort_t* __restrict__ s, int n)
{
    const int wid = threadIdx.x >> 6, lane = threadIdx.x & 63;
    const int nw = gridDim.x * 4;
    for (int node = blockIdx.x * 4 + wid; node < n; node += nw) {
        const int o0 = off[node], o1 = off[node + 1];
        float ax = 0.f, ay = 0.f;
        int j = o0;
        for (; j + 4 <= o1; j += 4) {
            const int s0 = csr[j], s1 = csr[j + 1], s2 = csr[j + 2], s3 = csr[j + 3];
            const uint_t v0 = *reinterpret_cast<const uint_t*>(hsrc + (size_t)s0 * HD + 2 * lane);
            const uint_t v1 = *reinterpret_cast<const uint_t*>(hsrc + (size_t)s1 * HD + 2 * lane);
            const uint_t v2 = *reinterpret_cast<const uint_t*>(hsrc + (size_t)s2 * HD + 2 * lane);
            const uint_t v3 = *reinterpret_cast<const uint_t*>(hsrc + (size_t)s3 * HD + 2 * lane);
            ax += bflo(v0) + bflo(v1) + bflo(v2) + bflo(v3);
            ay += bfhi(v0) + bfhi(v1) + bfhi(v2) + bfhi(v3);
        }
        for (; j < o1; ++j) {
            const uint_t v = *reinterpret_cast<const uint_t*>(hsrc + (size_t)csr[j] * HD + 2 * lane);
            ax += bflo(v); ay += bfhi(v);
        }
        const float inv = 1.0f / fmaxf((float)(o1 - o0), 1.0f);
        *reinterpret_cast<uint_t*>(s + (size_t)node * HD + 2 * lane) = pack2bf(ax * inv, ay * inv);
    }
}

// ---------------- Wsum = Wr_ba + Wr_aa ----------------
__global__ void wsum_kernel(const float* __restrict__ A, const float* __restrict__ B,
                            float* __restrict__ C)
{
    const int i = blockIdx.x * blockDim.x + threadIdx.x;
    if (i < HD * HD) C[i] = A[i] + B[i];
}

// ---------------- per-graph node counts ----------------
__global__ void gcnt_kernel(const int* __restrict__ batch, float* __restrict__ gcnt, int n)
{
    const int i = blockIdx.x * blockDim.x + threadIdx.x;
    if (i < n) unsafeAtomicAdd(gcnt + batch[i], 1.0f);
}

// ---------------- dst 'b': m = mean@Wl + h_b@Wr + bl ; relu ; pool ----------------
__global__ void __launch_bounds__(256)
fused_b_kernel(const ushort_t* __restrict__ s, const ushort_t* __restrict__ hb,
               const float* __restrict__ Wl, const float* __restrict__ bl,
               const float* __restrict__ Wr, const int* __restrict__ batch,
               float* __restrict__ pool)
{
    extern __shared__ float lds[];
    float* wl = lds;
    float* wr = lds + 16384;
    float* bs = lds + 32768;
    for (int i = threadIdx.x; i < 16384; i += 256) { wl[i] = Wl[i]; wr[i] = Wr[i]; }
    if (threadIdx.x < HD) bs[threadIdx.x] = bl[threadIdx.x];
    __syncthreads();
    const int wid = threadIdx.x >> 6, lane = threadIdx.x & 63;
    const int c0 = 2 * lane;
    const int wg = blockIdx.x * 4 + wid, nw = gridDim.x * 4;
    for (int n0 = wg * 2; n0 < NB; n0 += nw * 2) {
        const int n1 = min(n0 + 1, NB - 1);
        const ushort_t* s0 = s + (size_t)n0 * HD;
        const ushort_t* s1 = s + (size_t)n1 * HD;
        const ushort_t* h0 = hb + (size_t)n0 * HD;
        const ushort_t* h1 = hb + (size_t)n1 * HD;
        float a00 = bs[c0], a01 = bs[c0 + 1];
        float a10 = a00, a11 = a01;
#pragma unroll 4
        for (int k2 = 0; k2 < 64; ++k2) {
            const float2 wa0 = *reinterpret_cast<const float2*>(wl + (2 * k2) * HD + c0);
            const float2 wa1 = *reinterpret_cast<const float2*>(wl + (2 * k2 + 1) * HD + c0);
            const float2 wb0 = *reinterpret_cast<const float2*>(wr + (2 * k2) * HD + c0);
            const float2 wb1 = *reinterpret_cast<const float2*>(wr + (2 * k2 + 1) * HD + c0);
            const uint_t us0 = *reinterpret_cast<const uint_t*>(s0 + 2 * k2);
            const uint_t uh0 = *reinterpret_cast<const uint_t*>(h0 + 2 * k2);
            const uint_t us1 = *reinterpret_cast<const uint_t*>(s1 + 2 * k2);
            const uint_t uh1 = *reinterpret_cast<const uint_t*>(h1 + 2 * k2);
            const float x0a = bflo(us0), x0b = bfhi(us0);
            const float y0a = bflo(uh0), y0b = bfhi(uh0);
            const float x1a = bflo(us1), x1b = bfhi(us1);
            const float y1a = bflo(uh1), y1b = bfhi(uh1);
            a00 = fmaf(x0a, wa0.x, a00); a00 = fmaf(x0b, wa1.x, a00);
            a00 = fmaf(y0a, wb0.x, a00); a00 = fmaf(y0b, wb1.x, a00);
            a01 = fmaf(x0a, wa0.y, a01); a01 = fmaf(x0b, wa1.y, a01);
            a01 = fmaf(y0a, wb0.y, a01); a01 = fmaf(y0b, wb1.y, a01);
            a10 = fmaf(x1a, wa0.x, a10); a10 = fmaf(x1b, wa1.x, a10);
            a10 = fmaf(y1a, wb0.x, a10); a10 = fmaf(y1b, wb1.x, a10);
            a11 = fmaf(x1a, wa0.y, a11); a11 = fmaf(x1b, wa1.y, a11);
            a11 = fmaf(y1a, wb0.y, a11); a11 = fmaf(y1b, wb1.y, a11);
        }
        const int g0 = batch[n0];
        unsafeAtomicAdd(pool + g0 * HD + c0,     fmaxf(a00, 0.f));
        unsafeAtomicAdd(pool + g0 * HD + c0 + 1, fmaxf(a01, 0.f));
        if (n1 > n0) {
            const int g1 = batch[n1];
            unsafeAtomicAdd(pool + g1 * HD + c0,     fmaxf(a10, 0.f));
            unsafeAtomicAdd(pool + g1 * HD + c0 + 1, fmaxf(a11, 0.f));
        }
    }
}

// ---------------- dst 'a' pass A: t = mean_ba@Wl_ba + mean_aa@Wl_aa + (bl_ba+bl_aa)
// written in-place into s_ba (bf16; rows are wave-exclusive, read fully before write)
__global__ void __launch_bounds__(256)
passA_kernel(ushort_t* s_ba, const ushort_t* __restrict__ s_aa,
             const float* __restrict__ Wl1, const float* __restrict__ bl1,
             const float* __restrict__ Wl2, const float* __restrict__ bl2)
{
    extern __shared__ float lds[];
    float* w1 = lds;
    float* w2 = lds + 16384;
    float* bs = lds + 32768;
    for (int i = threadIdx.x; i < 16384; i += 256) { w1[i] = Wl1[i]; w2[i] = Wl2[i]; }
    if (threadIdx.x < HD) bs[threadIdx.x] = bl1[threadIdx.x] + bl2[threadIdx.x];
    __syncthreads();
    const int wid = threadIdx.x >> 6, lane = threadIdx.x & 63;
    const int c0 = 2 * lane;
    const int wg = blockIdx.x * 4 + wid, nw = gridDim.x * 4;
    for (int n0 = wg * 2; n0 < NA; n0 += nw * 2) {
        const int n1 = min(n0 + 1, NA - 1);
        ushort_t* t0 = s_ba + (size_t)n0 * HD;
        ushort_t* t1 = s_ba + (size_t)n1 * HD;
        const ushort_t* u0 = s_aa + (size_t)n0 * HD;
        const ushort_t* u1 = s_aa + (size_t)n1 * HD;
        float a00 = bs[c0], a01 = bs[c0 + 1];
        float a10 = a00, a11 = a01;
#pragma unroll 4
        for (int k2 = 0; k2 < 64; ++k2) {
            const float2 wa0 = *reinterpret_cast<const float2*>(w1 + (2 * k2) * HD + c0);
            const float2 wa1 = *reinterpret_cast<const float2*>(w1 + (2 * k2 + 1) * HD + c0);
            const float2 wb0 = *reinterpret_cast<const float2*>(w2 + (2 * k2) * HD + c0);
            const float2 wb1 = *reinterpret_cast<const float2*>(w2 + (2 * k2 + 1) * HD + c0);
            const uint_t ut0 = *reinterpret_cast<const uint_t*>(t0 + 2 * k2);
            const uint_t uu0 = *reinterpret_cast<const uint_t*>(u0 + 2 * k2);
            const uint_t ut1 = *reinterpret_cast<const uint_t*>(t1 + 2 * k2);
            const uint_t uu1 = *reinterpret_cast<const uint_t*>(u1 + 2 * k2);
            const float x0a = bflo(ut0), x0b = bfhi(ut0);
            const float y0a = bflo(uu0), y0b = bfhi(uu0);
            const float x1a = bflo(ut1), x1b = bfhi(ut1);
            const float y1a = bflo(uu1), y1b = bfhi(uu1);
            a00 = fmaf(x0a, wa0.x, a00); a00 = fmaf(x0b, wa1.x, a00);
            a00 = fmaf(y0a, wb0.x, a00); a00 = fmaf(y0b, wb1.x, a00);
            a01 = fmaf(x0a, wa0.y, a01); a01 = fmaf(x0b, wa1.y, a01);
            a01 = fmaf(y0a, wb0.y, a01); a01 = fmaf(y0b, wb1.y, a01);
            a10 = fmaf(x1a, wa0.x, a10); a10 = fmaf(x1b, wa1.x, a10);
            a10 = fmaf(y1a, wb0.x, a10); a10 = fmaf(y1b, wb1.x, a10);
            a11 = fmaf(x1a, wa0.y, a11); a11 = fmaf(x1b, wa1.y, a11);
            a11 = fmaf(y1a, wb0.y, a11); a11 = fmaf(y1b, wb1.y, a11);
        }
        *reinterpret_cast<uint_t*>(t0 + c0) = pack2bf(a00, a01);
        if (n1 > n0) *reinterpret_cast<uint_t*>(t1 + c0) = pack2bf(a10, a11);
    }
}

// ---------------- dst 'a' pass B: m = 0.5*(t + h_a@Wsum) ; relu ; pool ----------------
__global__ void __launch_bounds__(256)
passB_kernel(const ushort_t* __restrict__ t, const ushort_t* __restrict__ ha,
             const float* __restrict__ Wsum, const int* __restrict__ batch,
             float* __restrict__ pool)
{
    extern __shared__ float lds[];
    float* w = lds;
    for (int i = threadIdx.x; i < 16384; i += 256) w[i] = Wsum[i];
    __syncthreads();
    const int wid = threadIdx.x >> 6, lane = threadIdx.x & 63;
    const int c0 = 2 * lane;
    const int wg = blockIdx.x * 4 + wid, nw = gridDim.x * 4;
    for (int n0 = wg * 2; n0 < NA; n0 += nw * 2) {
        const int n1 = min(n0 + 1, NA - 1);
        const ushort_t* h0 = ha + (size_t)n0 * HD;
        const ushort_t* h1 = ha + (size_t)n1 * HD;
        float a00 = 0.f, a01 = 0.f, a10 = 0.f, a11 = 0.f;
#pragma unroll 4
        for (int k2 = 0; k2 < 64; ++k2) {
            const float2 w0 = *reinterpret_cast<const float2*>(w + (2 * k2) * HD + c0);
            const float2 w1v = *reinterpret_cast<const float2*>(w + (2 * k2 + 1) * HD + c0);
            const uint_t uh0 = *reinterpret_cast<const uint_t*>(h0 + 2 * k2);
            const uint_t uh1 = *reinterpret_cast<const uint_t*>(h1 + 2 * k2);
            const float x0a = bflo(uh0), x0b = bfhi(uh0);
            const float x1a = bflo(uh1), x1b = bfhi(uh1);
            a00 = fmaf(x0a, w0.x, a00); a00 = fmaf(x0b, w1v.x, a00);
            a01 = fmaf(x0a, w0.y, a01); a01 = fmaf(x0b, w1v.y, a01);
            a10 = fmaf(x1a, w0.x, a10); a10 = fmaf(x1b, w1v.x, a10);
            a11 = fmaf(x1a, w0.y, a11); a11 = fmaf(x1b, w1v.y, a11);
        }
        const uint_t t0v = *reinterpret_cast<const uint_t*>(t + (size_t)n0 * HD + c0);
        const float m00 = fmaxf(0.5f * (bflo(t0v) + a00), 0.f);
        const float m01 = fmaxf(0.5f * (bfhi(t0v) + a01), 0.f);
        const int g0 = batch[n0];
        unsafeAtomicAdd(pool + g0 * HD + c0,     m00);
        unsafeAtomicAdd(pool + g0 * HD + c0 + 1, m01);
        if (n1 > n0) {
            const uint_t t1v = *reinterpret_cast<const uint_t*>(t + (size_t)n1 * HD + c0);
            const float m10 = fmaxf(0.5f * (bflo(t1v) + a10), 0.f);
            const float m11 = fmaxf(0.5f * (bfhi(t1v) + a11), 0.f);
            const int g1 = batch[n1];
            unsafeAtomicAdd(pool + g1 * HD + c0,     m10);
            unsafeAtomicAdd(pool + g1 * HD + c0 + 1, m11);
        }
    }
}

// ---------------- head: out = (0.5*(pa/ga + pb/gb)) @ Wout + bout ----------------
__global__ void final_kernel(const float* __restrict__ pa, const float* __restrict__ pb,
                             const float* __restrict__ ga, const float* __restrict__ gb,
                             const float* __restrict__ Wout, const float* __restrict__ bout,
                             float* __restrict__ out)
{
    const int g = blockIdx.x;
    const int lane = threadIdx.x;
    const float inva = 1.0f / fmaxf(ga[g], 1.0f);
    const float invb = 1.0f / fmaxf(gb[g], 1.0f);
    if (lane < OUTD) {
        float acc = bout[lane];
        for (int k = 0; k < HD; ++k) {
            const float x = 0.5f * (pa[g * HD + k] * inva + pb[g * HD + k] * invb);
            acc = fmaf(x, Wout[k * OUTD + lane], acc);
        }
        out[g * OUTD + lane] = acc;
    }
}

extern "C" void kernel_launch(void* const* d_in, const int* in_sizes, int n_in,
                              void* d_out, int out_size, void* d_ws, size_t ws_size,
                              hipStream_t stream)
{
    const float* x_a     = (const float*)d_in[0];
    const float* x_b     = (const float*)d_in[1];
    const int*   ei_ab   = (const int*)d_in[2];
    const int*   ei_ba   = (const int*)d_in[3];
    const int*   ei_aa   = (const int*)d_in[4];
    const int*   batch_a = (const int*)d_in[5];
    const int*   batch_b = (const int*)d_in[6];
    const float* Wemb_a  = (const float*)d_in[7];
    const float* bemb_a  = (const float*)d_in[8];
    const float* Wemb_b  = (const float*)d_in[9];
    const float* bemb_b  = (const float*)d_in[10];
    const float* Wl_ab   = (const float*)d_in[11];
    const float* bl_ab   = (const float*)d_in[12];
    const float* Wr_ab   = (const float*)d_in[13];
    const float* Wl_ba   = (const float*)d_in[14];
    const float* bl_ba   = (const float*)d_in[15];
    const float* Wr_ba   = (const float*)d_in[16];
    const float* Wl_aa   = (const float*)d_in[17];
    const float* bl_aa   = (const float*)d_in[18];
    const float* Wr_aa   = (const float*)d_in[19];
    const float* Wout    = (const float*)d_in[20];
    const float* bout    = (const float*)d_in[21];
    float* out = (float*)d_out;

    // ---------------- workspace layout (bytes) ----------------
    char* p = (char*)d_ws;
    ushort_t* h_a  = (ushort_t*)p; p += (size_t)NA * HD * 2;   // 25.6 MB
    ushort_t* h_b  = (ushort_t*)p; p += (size_t)NB * HD * 2;   // 25.6 MB
    ushort_t* s_ab = (ushort_t*)p; p += (size_t)NB * HD * 2;   // 25.6 MB
    ushort_t* s_ba = (ushort_t*)p; p += (size_t)NA * HD * 2;   // 25.6 MB (reused as t)
    ushort_t* s_aa = (ushort_t*)p; p += (size_t)NA * HD * 2;   // 25.6 MB
    int* csr  = (int*)p; p += (size_t)NEDGE * 4;               // 6.4 MB (shared across relations)
    int* deg  = (int*)p; p += (size_t)NA * 4;
    int* off  = (int*)p; p += (size_t)(NA + 1) * 4;
    int* cur  = (int*)p; p += (size_t)NA * 4;
    int* bsum = (int*)p; p += 128 * 4;
    int* bscan= (int*)p; p += 128 * 4;
    float* pool_a = (float*)p; p += (size_t)NG * HD * 4;
    float* pool_b = (float*)p; p += (size_t)NG * HD * 4;
    float* gcnt_a = (float*)p; p += NG * 4;
    float* gcnt_b = (float*)p; p += NG * 4;
    float* wsum   = (float*)p; p += (size_t)HD * HD * 4;

    const int NBLK = (NA + SCAN_ITEMS - 1) / SCAN_ITEMS;       // 98 (same for NB)
    const int EGRID = (NEDGE + 255) / 256;

    // zero pool accumulators (contiguous: pool_a, pool_b, gcnt_a, gcnt_b)
    hipMemsetAsync(pool_a, 0, ((size_t)2 * NG * HD + 2 * NG) * 4, stream);

    wsum_kernel<<<(HD * HD + 255) / 256, 256, 0, stream>>>(Wr_ba, Wr_aa, wsum);
    emb_kernel<DA><<<(NA + 3) / 4, 256, 0, stream>>>(x_a, Wemb_a, bemb_a, h_a, NA);
    emb_kernel<DB><<<(NB + 3) / 4, 256, 0, stream>>>(x_b, Wemb_b, bemb_b, h_b, NB);
    gcnt_kernel<<<(NA + 255) / 256, 256, 0, stream>>>(batch_a, gcnt_a, NA);
    gcnt_kernel<<<(NB + 255) / 256, 256, 0, stream>>>(batch_b, gcnt_b, NB);

    // ---- relation ab: src a -> dst b ----
    hipMemsetAsync(deg, 0, (size_t)NB * 4, stream);
    deg_kernel<<<EGRID, 256, 0, stream>>>(ei_ab, deg);
    scan1_kernel<<<NBLK, 256, 0, stream>>>(deg, bsum, NB);
    scan2_kernel<<<1, 128, 0, stream>>>(bsum, bscan, NBLK, off + NB);
    scan3_kernel<<<NBLK, 256, 0, stream>>>(deg, bscan, off, cur, NB);
    fill_kernel<<<EGRID, 256, 0, stream>>>(ei_ab, cur, csr);
    gather_kernel<<<2048, 256, 0, stream>>>(h_a, csr, off, s_ab, NB);

    // ---- relation ba: src b -> dst a ----
    hipMemsetAsync(deg, 0, (size_t)NA * 4, stream);
    deg_kernel<<<EGRID, 256, 0, stream>>>(ei_ba, deg);
    scan1_kernel<<<NBLK, 256, 0, stream>>>(deg, bsum, NA);
    scan2_kernel<<<1, 128, 0, stream>>>(bsum, bscan, NBLK, off + NA);
    scan3_kernel<<<NBLK, 256, 0, stream>>>(deg, bscan, off, cur, NA);
    fill_kernel<<<EGRID, 256, 0, stream>>>(ei_ba, cur, csr);
    gather_kernel<<<2048, 256, 0, stream>>>(h_b, csr, off, s_ba, NA);

    // ---- relation aa: src a -> dst a ----
    hipMemsetAsync(deg, 0, (size_t)NA * 4, stream);
    deg_kernel<<<EGRID, 256, 0, stream>>>(ei_aa, deg);
    scan1_kernel<<<NBLK, 256, 0, stream>>>(deg, bsum, NA);
    scan2_kernel<<<1, 128, 0, stream>>>(bsum, bscan, NBLK, off + NA);
    scan3_kernel<<<NBLK, 256, 0, stream>>>(deg, bscan, off, cur, NA);
    fill_kernel<<<EGRID, 256, 0, stream>>>(ei_aa, cur, csr);
    gather_kernel<<<2048, 256, 0, stream>>>(h_a, csr, off, s_aa, NA);

    // ---- fused per-node GEMMs + relu + pool ----
    const int lds_big   = (16384 * 2 + 128) * 4;   // 131584 B
    const int lds_small = 16384 * 4;               // 65536 B
    hipFuncSetAttribute((const void*)fused_b_kernel, hipFuncAttributeMaxDynamicSharedMemorySize, lds_big);
    hipFuncSetAttribute((const void*)passA_kernel,   hipFuncAttributeMaxDynamicSharedMemorySize, lds_big);
    hipFuncSetAttribute((const void*)passB_kernel,   hipFuncAttributeMaxDynamicSharedMemorySize, lds_small);

    fused_b_kernel<<<512, 256, lds_big, stream>>>(s_ab, h_b, Wl_ab, bl_ab, Wr_ab, batch_b, pool_b);
    passA_kernel  <<<512, 256, lds_big, stream>>>(s_ba, s_aa, Wl_ba, bl_ba, Wl_aa, bl_aa);
    passB_kernel  <<<512, 256, lds_small, stream>>>(s_ba, h_a, wsum, batch_a, pool_a);

    final_kernel<<<NG, 64, 0, stream>>>(pool_a, pool_b, gcnt_a, gcnt_b, Wout, bout, out);
}

// Round 3
// 1546.805 us; speedup vs baseline: 6.3942x; 1.3673x over previous
//
#include <hip/hip_runtime.h>

#define NA 100000
#define NB 100000
#define NEDGE 1600000
#define HD 128
#define OUTD 16
#define NG 256
#define DA 64
#define DB 32
#define SCAN_ITEMS 1024
#define PG 16

typedef unsigned int uint_t;
typedef unsigned short ushort_t;
typedef __bf16 bf16_t;
typedef bf16_t bf16x8 __attribute__((ext_vector_type(8)));
typedef float f32x4 __attribute__((ext_vector_type(4)));

__device__ __forceinline__ float bflo(uint_t u) {
    union { uint_t i; float f; } c; c.i = u << 16; return c.f;
}
__device__ __forceinline__ float bfhi(uint_t u) {
    union { uint_t i; float f; } c; c.i = u & 0xffff0000u; return c.f;
}
__device__ __forceinline__ uint_t f2bf(float f) {
    union { float f; uint_t i; } c; c.f = f;
    uint_t r = c.i + 0x7FFFu + ((c.i >> 16) & 1u);
    return r >> 16;
}
__device__ __forceinline__ uint_t pack2bf(float lo, float hi) {
    return f2bf(lo) | (f2bf(hi) << 16);
}

// ---------------- input embedding: h = x @ W + b  (K -> 128), bf16 out ----------------
template<int K>
__global__ void __launch_bounds__(256)
emb_kernel(const float* __restrict__ x, const float* __restrict__ W,
           const float* __restrict__ bias, ushort_t* __restrict__ h, int n)
{
    __shared__ float Ws[K * HD];
    __shared__ float bs[HD];
    for (int i = threadIdx.x; i < K * HD; i += 256) Ws[i] = W[i];
    if (threadIdx.x < HD) bs[threadIdx.x] = bias[threadIdx.x];
    __syncthreads();
    const int wid = threadIdx.x >> 6, lane = threadIdx.x & 63;
    const int c0 = 2 * lane;
    for (int row = blockIdx.x * 4 + wid; row < n; row += gridDim.x * 4) {
        const float* xr = x + (size_t)row * K;
        float a0 = bs[c0], a1 = bs[c0 + 1];
#pragma unroll 8
        for (int k = 0; k < K; ++k) {
            const float xv = xr[k];
            const float2 w = *reinterpret_cast<const float2*>(Ws + k * HD + c0);
            a0 = fmaf(xv, w.x, a0);
            a1 = fmaf(xv, w.y, a1);
        }
        *reinterpret_cast<uint_t*>(h + (size_t)row * HD + c0) = pack2bf(a0, a1);
    }
}

// ---------------- CSR build ----------------
__global__ void __launch_bounds__(256)
deg_kernel(const int* __restrict__ ei, int* __restrict__ deg)
{
    const int e = blockIdx.x * 256 + threadIdx.x;
    if (e < NEDGE) atomicAdd(&deg[ei[NEDGE + e]], 1);
}

__global__ void __launch_bounds__(256)
scan1_kernel(const int* __restrict__ deg, int* __restrict__ bsum, int n)
{
    __shared__ int red[256];
    const int base = blockIdx.x * SCAN_ITEMS + threadIdx.x * 4;
    int s = 0;
#pragma unroll
    for (int j = 0; j < 4; ++j) { const int i = base + j; if (i < n) s += deg[i]; }
    red[threadIdx.x] = s; __syncthreads();
    for (int d = 128; d > 0; d >>= 1) {
        if (threadIdx.x < d) red[threadIdx.x] += red[threadIdx.x + d];
        __syncthreads();
    }
    if (threadIdx.x == 0) bsum[blockIdx.x] = red[0];
}

__global__ void __launch_bounds__(128)
scan2_kernel(const int* __restrict__ bsum, int* __restrict__ bscan, int nblk, int* __restrict__ off_last)
{
    __shared__ int sc[128];
    const int t = threadIdx.x;
    const int v = (t < nblk) ? bsum[t] : 0;
    sc[t] = v; __syncthreads();
    for (int d = 1; d < 128; d <<= 1) {
        const int x = (t >= d) ? sc[t - d] : 0;
        __syncthreads();
        sc[t] += x;
        __syncthreads();
    }
    if (t < nblk) bscan[t] = sc[t] - v;          // exclusive
    if (t == nblk - 1) *off_last = sc[t];        // total = E
}

__global__ void __launch_bounds__(256)
scan3_kernel(const int* __restrict__ deg, const int* __restrict__ bscan,
             int* __restrict__ off, int* __restrict__ cur, int n)
{
    __shared__ int red[256];
    const int t = threadIdx.x;
    const int base = blockIdx.x * SCAN_ITEMS + t * 4;
    int v[4]; int s = 0;
#pragma unroll
    for (int j = 0; j < 4; ++j) { const int i = base + j; v[j] = (i < n) ? deg[i] : 0; s += v[j]; }
    red[t] = s; __syncthreads();
    for (int d = 1; d < 256; d <<= 1) {
        const int x = (t >= d) ? red[t - d] : 0;
        __syncthreads();
        red[t] += x;
        __syncthreads();
    }
    int ex = red[t] - s + bscan[blockIdx.x];
#pragma unroll
    for (int j = 0; j < 4; ++j) {
        const int i = base + j;
        if (i < n) { off[i] = ex; cur[i] = ex; }
        ex += v[j];
    }
}

__global__ void __launch_bounds__(256)
fill_kernel(const int* __restrict__ ei, int* __restrict__ cur, int* __restrict__ csr)
{
    const int e = blockIdx.x * 256 + threadIdx.x;
    if (e >= NEDGE) return;
    const int dst = ei[NEDGE + e];
    const int pos = atomicAdd(&cur[dst], 1);
    csr[pos] = ei[e];
}

// ---------------- gather-aggregate: s[n] = mean over edges of h[src], bf16 ----------------
__global__ void __launch_bounds__(256)
gather_kernel(const ushort_t* __restrict__ hsrc, const int* __restrict__ csr,
              const int* __restrict__ off, ushort_t* __restrict__ s, int n)
{
    const int wid = threadIdx.x >> 6, lane = threadIdx.x & 63;
    const int nw = gridDim.x * 4;
    for (int node = blockIdx.x * 4 + wid; node < n; node += nw) {
        const int o0 = off[node], o1 = off[node + 1];
        float ax = 0.f, ay = 0.f;
        int j = o0;
        for (; j + 4 <= o1; j += 4) {
            const int s0 = csr[j], s1 = csr[j + 1], s2 = csr[j + 2], s3 = csr[j + 3];
            const uint_t v0 = *reinterpret_cast<const uint_t*>(hsrc + (size_t)s0 * HD + 2 * lane);
            const uint_t v1 = *reinterpret_cast<const uint_t*>(hsrc + (size_t)s1 * HD + 2 * lane);
            const uint_t v2 = *reinterpret_cast<const uint_t*>(hsrc + (size_t)s2 * HD + 2 * lane);
            const uint_t v3 = *reinterpret_cast<const uint_t*>(hsrc + (size_t)s3 * HD + 2 * lane);
            ax += bflo(v0) + bflo(v1) + bflo(v2) + bflo(v3);
            ay += bfhi(v0) + bfhi(v1) + bfhi(v2) + bfhi(v3);
        }
        for (; j < o1; ++j) {
            const uint_t v = *reinterpret_cast<const uint_t*>(hsrc + (size_t)csr[j] * HD + 2 * lane);
            ax += bflo(v); ay += bfhi(v);
        }
        const float inv = 1.0f / fmaxf((float)(o1 - o0), 1.0f);
        *reinterpret_cast<uint_t*>(s + (size_t)node * HD + 2 * lane) = pack2bf(ax * inv, ay * inv);
    }
}

// ---------------- per-graph node counts ----------------
__global__ void gcnt_kernel(const int* __restrict__ batch, float* __restrict__ gcnt, int n)
{
    const int i = blockIdx.x * blockDim.x + threadIdx.x;
    if (i < n) unsafeAtomicAdd(gcnt + batch[i], 1.0f);
}

// ---------------- weight prep: W^T, bf16, XOR-swizzled (chunk ^= n&7) ----------------
// m=0: Wl_ab -> wt_fb[0]; m=1: Wr_ab -> wt_fb[1]; m=2: Wl_ba -> wt_pa[0];
// m=3: Wl_aa -> wt_pa[1]; m=4: (Wr_ba + Wr_aa) -> wt_pb[0]
__global__ void __launch_bounds__(256)
prep_w_kernel(const float* __restrict__ Wl_ab, const float* __restrict__ Wr_ab,
              const float* __restrict__ Wl_ba, const float* __restrict__ Wl_aa,
              const float* __restrict__ Wr_ba, const float* __restrict__ Wr_aa,
              ushort_t* __restrict__ wt_fb, ushort_t* __restrict__ wt_pa,
              ushort_t* __restrict__ wt_pb)
{
    const int m = blockIdx.x >> 3;
    const int id = (blockIdx.x & 7) * 256 + threadIdx.x;   // 0..2047
    const int nn = id >> 4, ck = id & 15;
    const float* src = (m == 0) ? Wl_ab : (m == 1) ? Wr_ab : (m == 2) ? Wl_ba
                     : (m == 3) ? Wl_aa : Wr_ba;
    ushort_t* dst = (m < 2) ? (wt_fb + m * 16384)
                  : (m < 4) ? (wt_pa + (m - 2) * 16384) : wt_pb;
    __align__(16) ushort_t tmp[8];
#pragma unroll
    for (int j = 0; j < 8; ++j) {
        const int k = ck * 8 + j;
        float v = src[k * HD + nn];
        if (m == 4) v += Wr_aa[k * HD + nn];
        tmp[j] = (ushort_t)f2bf(v);
    }
    const int cks = ck ^ (nn & 7);
    *reinterpret_cast<uint4*>(dst + nn * HD + cks * 8) = *reinterpret_cast<const uint4*>(tmp);
}

__global__ void bias_add_kernel(const float* __restrict__ a, const float* __restrict__ b,
                                float* __restrict__ c)
{
    const int i = threadIdx.x;
    if (i < HD) c[i] = a[i] + b[i];
}

// ---------------- MFMA fused GEMM: C = sum_s X_s @ W_s + bias, epilogue per MODE ----
// MODE 0: relu + pool-atomics (batch)          [fused_b]
// MODE 1: store f32 to outp (no relu/scale)    [passA -> t]
// MODE 2: 0.5*(acc + t_add), relu, pool        [passB]
template<int NSRC, int MODE>
__global__ void __launch_bounds__(256)
mfma_fused(const ushort_t* __restrict__ x0, const ushort_t* __restrict__ x1,
           const float* __restrict__ t_add,
           const ushort_t* __restrict__ wts, const float* __restrict__ bias,
           const int* __restrict__ batch, float* __restrict__ outp, int n)
{
    extern __shared__ char smem[];
    ushort_t* wlds   = (ushort_t*)smem;                    // NSRC*16384 bf16 (swizzled W^T)
    float* bias_lds  = (float*)(smem + NSRC * 32768);      // 128 f32
    float* poolbuf   = bias_lds + HD;                      // PG*128 f32 (MODE != 1)

    for (int i = threadIdx.x * 8; i < NSRC * 16384; i += 256 * 8)
        *reinterpret_cast<uint4*>(wlds + i) = *reinterpret_cast<const uint4*>(wts + i);
    if (threadIdx.x < HD) bias_lds[threadIdx.x] = bias ? bias[threadIdx.x] : 0.f;
    if (MODE != 1)
        for (int i = threadIdx.x; i < PG * HD; i += 256) poolbuf[i] = 0.f;
    __syncthreads();

    const int l  = threadIdx.x & 63, w = threadIdx.x >> 6;
    const int lo = l & 15, hi = l >> 4;
    const int row_base = blockIdx.x * 128 + w * 32;

    f32x4 acc[2][8];
    const f32x4 zero = {0.f, 0.f, 0.f, 0.f};
#pragma unroll
    for (int mi = 0; mi < 2; ++mi)
#pragma unroll
        for (int ni = 0; ni < 8; ++ni) acc[mi][ni] = zero;

#pragma unroll
    for (int s = 0; s < NSRC; ++s) {
        const ushort_t* xs = (s == 0) ? x0 : x1;
        bf16x8 a[2][4];
#pragma unroll
        for (int mi = 0; mi < 2; ++mi) {
            int r = row_base + mi * 16 + lo;
            r = min(r, n - 1);
            const ushort_t* xr = xs + (size_t)r * HD + hi * 8;
#pragma unroll
            for (int kk = 0; kk < 4; ++kk)
                a[mi][kk] = *reinterpret_cast<const bf16x8*>(xr + kk * 32);
        }
        const ushort_t* wb = wlds + s * 16384;
#pragma unroll
        for (int kk = 0; kk < 4; ++kk) {
#pragma unroll
            for (int ni = 0; ni < 8; ++ni) {
                const int nn = ni * 16 + lo;
                const int ck = (kk * 4 + hi) ^ (nn & 7);
                const bf16x8 b = *reinterpret_cast<const bf16x8*>(wb + nn * HD + ck * 8);
                acc[0][ni] = __builtin_amdgcn_mfma_f32_16x16x32_bf16(a[0][kk], b, acc[0][ni], 0, 0, 0);
                acc[1][ni] = __builtin_amdgcn_mfma_f32_16x16x32_bf16(a[1][kk], b, acc[1][ni], 0, 0, 0);
            }
        }
    }

    const int gmin = (MODE != 1) ? batch[blockIdx.x * 128] : 0;

#pragma unroll
    for (int mi = 0; mi < 2; ++mi) {
#pragma unroll
        for (int ni = 0; ni < 8; ++ni) {
            const int col = ni * 16 + lo;
            const float bv = bias_lds[col];
            const f32x4 v = acc[mi][ni];
#pragma unroll
            for (int r = 0; r < 4; ++r) {
                const int row = row_base + mi * 16 + hi * 4 + r;
                if (row < n) {
                    float val = v[r] + bv;
                    if (MODE == 1) {
                        outp[(size_t)row * HD + col] = val;
                    } else {
                        if (MODE == 2) val = 0.5f * (val + t_add[(size_t)row * HD + col]);
                        val = fmaxf(val, 0.f);
                        const int g = batch[row];
                        const unsigned slot = (unsigned)(g - gmin);
                        if (slot < PG) atomicAdd(&poolbuf[slot * HD + col], val);
                        else unsafeAtomicAdd(outp + (size_t)g * HD + col, val);
                    }
                }
            }
        }
    }
    if (MODE != 1) {
        __syncthreads();
        for (int i = threadIdx.x; i < PG * HD; i += 256) {
            const float v = poolbuf[i];
            if (v != 0.f) {
                const int g = gmin + (i >> 7);
                if (g < NG) unsafeAtomicAdd(outp + (size_t)g * HD + (i & 127), v);
            }
        }
    }
}

// ---------------- head: out = (0.5*(pa/ga + pb/gb)) @ Wout + bout ----------------
__global__ void final_kernel(const float* __restrict__ pa, const float* __restrict__ pb,
                             const float* __restrict__ ga, const float* __restrict__ gb,
                             const float* __restrict__ Wout, const float* __restrict__ bout,
                             float* __restrict__ out)
{
    const int g = blockIdx.x;
    const int lane = threadIdx.x;
    const float inva = 1.0f / fmaxf(ga[g], 1.0f);
    const float invb = 1.0f / fmaxf(gb[g], 1.0f);
    if (lane < OUTD) {
        float acc = bout[lane];
        for (int k = 0; k < HD; ++k) {
            const float x = 0.5f * (pa[g * HD + k] * inva + pb[g * HD + k] * invb);
            acc = fmaf(x, Wout[k * OUTD + lane], acc);
        }
        out[g * OUTD + lane] = acc;
    }
}

extern "C" void kernel_launch(void* const* d_in, const int* in_sizes, int n_in,
                              void* d_out, int out_size, void* d_ws, size_t ws_size,
                              hipStream_t stream)
{
    const float* x_a     = (const float*)d_in[0];
    const float* x_b     = (const float*)d_in[1];
    const int*   ei_ab   = (const int*)d_in[2];
    const int*   ei_ba   = (const int*)d_in[3];
    const int*   ei_aa   = (const int*)d_in[4];
    const int*   batch_a = (const int*)d_in[5];
    const int*   batch_b = (const int*)d_in[6];
    const float* Wemb_a  = (const float*)d_in[7];
    const float* bemb_a  = (const float*)d_in[8];
    const float* Wemb_b  = (const float*)d_in[9];
    const float* bemb_b  = (const float*)d_in[10];
    const float* Wl_ab   = (const float*)d_in[11];
    const float* bl_ab   = (const float*)d_in[12];
    const float* Wr_ab   = (const float*)d_in[13];
    const float* Wl_ba   = (const float*)d_in[14];
    const float* bl_ba   = (const float*)d_in[15];
    const float* Wr_ba   = (const float*)d_in[16];
    const float* Wl_aa   = (const float*)d_in[17];
    const float* bl_aa   = (const float*)d_in[18];
    const float* Wr_aa   = (const float*)d_in[19];
    const float* Wout    = (const float*)d_in[20];
    const float* bout    = (const float*)d_in[21];
    float* out = (float*)d_out;

    // ---------------- workspace layout ----------------
    char* p = (char*)d_ws;
    ushort_t* h_a  = (ushort_t*)p; p += (size_t)NA * HD * 2;
    ushort_t* h_b  = (ushort_t*)p; p += (size_t)NB * HD * 2;
    ushort_t* s_ab = (ushort_t*)p; p += (size_t)NB * HD * 2;
    ushort_t* s_ba = (ushort_t*)p; p += (size_t)NA * HD * 2;
    ushort_t* s_aa = (ushort_t*)p; p += (size_t)NA * HD * 2;
    float* t       = (float*)p;    p += (size_t)NA * HD * 4;   // 51.2 MB
    int* csr  = (int*)p; p += (size_t)NEDGE * 4;
    int* deg  = (int*)p; p += (size_t)NA * 4;
    int* off  = (int*)p; p += (size_t)(NA + 4) * 4;            // padded to 16B
    int* cur  = (int*)p; p += (size_t)NA * 4;
    int* bsum = (int*)p; p += 128 * 4;
    int* bscan= (int*)p; p += 128 * 4;
    float* pool_a = (float*)p; p += (size_t)NG * HD * 4;
    float* pool_b = (float*)p; p += (size_t)NG * HD * 4;
    float* gcnt_a = (float*)p; p += NG * 4;
    float* gcnt_b = (float*)p; p += NG * 4;
    ushort_t* wt_fb = (ushort_t*)p; p += 2 * 16384 * 2;
    ushort_t* wt_pa = (ushort_t*)p; p += 2 * 16384 * 2;
    ushort_t* wt_pb = (ushort_t*)p; p += 1 * 16384 * 2;
    float* bias_pa  = (float*)p;    p += HD * 4;

    const int NBLK = (NA + SCAN_ITEMS - 1) / SCAN_ITEMS;       // 98
    const int EGRID = (NEDGE + 255) / 256;
    const int GT = (NA + 127) / 128;                           // 782

    // zero pool accumulators (contiguous: pool_a, pool_b, gcnt_a, gcnt_b)
    hipMemsetAsync(pool_a, 0, ((size_t)2 * NG * HD + 2 * NG) * 4, stream);

    prep_w_kernel<<<40, 256, 0, stream>>>(Wl_ab, Wr_ab, Wl_ba, Wl_aa, Wr_ba, Wr_aa,
                                          wt_fb, wt_pa, wt_pb);
    bias_add_kernel<<<1, 128, 0, stream>>>(bl_ba, bl_aa, bias_pa);

    emb_kernel<DA><<<(NA + 3) / 4, 256, 0, stream>>>(x_a, Wemb_a, bemb_a, h_a, NA);
    emb_kernel<DB><<<(NB + 3) / 4, 256, 0, stream>>>(x_b, Wemb_b, bemb_b, h_b, NB);
    gcnt_kernel<<<(NA + 255) / 256, 256, 0, stream>>>(batch_a, gcnt_a, NA);
    gcnt_kernel<<<(NB + 255) / 256, 256, 0, stream>>>(batch_b, gcnt_b, NB);

    // ---- relation ab: src a -> dst b ----
    hipMemsetAsync(deg, 0, (size_t)NB * 4, stream);
    deg_kernel<<<EGRID, 256, 0, stream>>>(ei_ab, deg);
    scan1_kernel<<<NBLK, 256, 0, stream>>>(deg, bsum, NB);
    scan2_kernel<<<1, 128, 0, stream>>>(bsum, bscan, NBLK, off + NB);
    scan3_kernel<<<NBLK, 256, 0, stream>>>(deg, bscan, off, cur, NB);
    fill_kernel<<<EGRID, 256, 0, stream>>>(ei_ab, cur, csr);
    gather_kernel<<<2048, 256, 0, stream>>>(h_a, csr, off, s_ab, NB);

    // ---- relation ba: src b -> dst a ----
    hipMemsetAsync(deg, 0, (size_t)NA * 4, stream);
    deg_kernel<<<EGRID, 256, 0, stream>>>(ei_ba, deg);
    scan1_kernel<<<NBLK, 256, 0, stream>>>(deg, bsum, NA);
    scan2_kernel<<<1, 128, 0, stream>>>(bsum, bscan, NBLK, off + NA);
    scan3_kernel<<<NBLK, 256, 0, stream>>>(deg, bscan, off, cur, NA);
    fill_kernel<<<EGRID, 256, 0, stream>>>(ei_ba, cur, csr);
    gather_kernel<<<2048, 256, 0, stream>>>(h_b, csr, off, s_ba, NA);

    // ---- relation aa: src a -> dst a ----
    hipMemsetAsync(deg, 0, (size_t)NA * 4, stream);
    deg_kernel<<<EGRID, 256, 0, stream>>>(ei_aa, deg);
    scan1_kernel<<<NBLK, 256, 0, stream>>>(deg, bsum, NA);
    scan2_kernel<<<1, 128, 0, stream>>>(bsum, bscan, NBLK, off + NA);
    scan3_kernel<<<NBLK, 256, 0, stream>>>(deg, bscan, off, cur, NA);
    fill_kernel<<<EGRID, 256, 0, stream>>>(ei_aa, cur, csr);
    gather_kernel<<<2048, 256, 0, stream>>>(h_a, csr, off, s_aa, NA);

    // ---- MFMA fused GEMMs ----
    const int lds_fb = 2 * 32768 + 512 + PG * HD * 4;   // 74240
    const int lds_pa = 2 * 32768 + 512;                 // 66048
    const int lds_pb = 1 * 32768 + 512 + PG * HD * 4;   // 41472
    hipFuncSetAttribute((const void*)mfma_fused<2, 0>, hipFuncAttributeMaxDynamicSharedMemorySize, lds_fb);
    hipFuncSetAttribute((const void*)mfma_fused<2, 1>, hipFuncAttributeMaxDynamicSharedMemorySize, lds_pa);
    hipFuncSetAttribute((const void*)mfma_fused<1, 2>, hipFuncAttributeMaxDynamicSharedMemorySize, lds_pb);

    // dst 'b': relu(s_ab@Wl_ab + h_b@Wr_ab + bl_ab) -> pool_b
    mfma_fused<2, 0><<<GT, 256, lds_fb, stream>>>(s_ab, h_b, nullptr, wt_fb, bl_ab, batch_b, pool_b, NB);
    // dst 'a' pass A: t = s_ba@Wl_ba + s_aa@Wl_aa + (bl_ba+bl_aa)   (f32)
    mfma_fused<2, 1><<<GT, 256, lds_pa, stream>>>(s_ba, s_aa, nullptr, wt_pa, bias_pa, nullptr, t, NA);
    // dst 'a' pass B: relu(0.5*(t + h_a@(Wr_ba+Wr_aa))) -> pool_a
    mfma_fused<1, 2><<<GT, 256, lds_pb, stream>>>(h_a, nullptr, t, wt_pb, nullptr, batch_a, pool_a, NA);

    final_kernel<<<NG, 64, 0, stream>>>(pool_a, pool_b, gcnt_a, gcnt_b, Wout, bout, out);
}

// Round 4
// 1191.926 us; speedup vs baseline: 8.2979x; 1.2977x over previous
//
#include <hip/hip_runtime.h>

#define NA 100000
#define NB 100000
#define NEDGE 1600000
#define HD 128
#define OUTD 16
#define NG 256
#define DA 64
#define DB 32
#define SCAN_ITEMS 1024
#define PG 16

typedef unsigned int uint_t;
typedef unsigned short ushort_t;
typedef __bf16 bf16_t;
typedef bf16_t bf16x8 __attribute__((ext_vector_type(8)));
typedef float f32x4 __attribute__((ext_vector_type(4)));

__device__ __forceinline__ float bflo(uint_t u) {
    union { uint_t i; float f; } c; c.i = u << 16; return c.f;
}
__device__ __forceinline__ float bfhi(uint_t u) {
    union { uint_t i; float f; } c; c.i = u & 0xffff0000u; return c.f;
}
__device__ __forceinline__ uint_t f2bf(float f) {
    union { float f; uint_t i; } c; c.f = f;
    uint_t r = c.i + 0x7FFFu + ((c.i >> 16) & 1u);
    return r >> 16;
}
__device__ __forceinline__ uint_t pack2bf(float lo, float hi) {
    return f2bf(lo) | (f2bf(hi) << 16);
}

// ---------------- input embedding: h = x @ W + b  (K -> 128), bf16 out ----------------
template<int K>
__global__ void __launch_bounds__(256)
emb_kernel(const float* __restrict__ x, const float* __restrict__ W,
           const float* __restrict__ bias, ushort_t* __restrict__ h, int n)
{
    __shared__ float Ws[K * HD];
    __shared__ float bs[HD];
    for (int i = threadIdx.x; i < K * HD; i += 256) Ws[i] = W[i];
    if (threadIdx.x < HD) bs[threadIdx.x] = bias[threadIdx.x];
    __syncthreads();
    const int wid = threadIdx.x >> 6, lane = threadIdx.x & 63;
    const int c0 = 2 * lane;
    for (int row = blockIdx.x * 4 + wid; row < n; row += gridDim.x * 4) {
        const float* xr = x + (size_t)row * K;
        float a0 = bs[c0], a1 = bs[c0 + 1];
#pragma unroll 8
        for (int k = 0; k < K; ++k) {
            const float xv = xr[k];
            const float2 w = *reinterpret_cast<const float2*>(Ws + k * HD + c0);
            a0 = fmaf(xv, w.x, a0);
            a1 = fmaf(xv, w.y, a1);
        }
        *reinterpret_cast<uint_t*>(h + (size_t)row * HD + c0) = pack2bf(a0, a1);
    }
}

// ---------------- per-graph node counts via binary search (batch is sorted) --------
__global__ void __launch_bounds__(256)
gcount_kernel(const int* __restrict__ batch_a, const int* __restrict__ batch_b,
              float* __restrict__ ga, float* __restrict__ gb)
{
    const int g = threadIdx.x;              // 0..255
    const int* batch = blockIdx.x ? batch_b : batch_a;
    float* outp = blockIdx.x ? gb : ga;
    const int n = blockIdx.x ? NB : NA;
    int lo0 = 0, hi0 = n;                   // lower_bound(g)
    while (lo0 < hi0) { const int mid = (lo0 + hi0) >> 1; if (batch[mid] < g) lo0 = mid + 1; else hi0 = mid; }
    int lo1 = 0, hi1 = n;                   // lower_bound(g+1)
    while (lo1 < hi1) { const int mid = (lo1 + hi1) >> 1; if (batch[mid] < g + 1) lo1 = mid + 1; else hi1 = mid; }
    outp[g] = (float)(lo1 - lo0);
}

// ---------------- merged CSR build for all 3 relations ----------------
__global__ void __launch_bounds__(256)
deg3_kernel(const int* __restrict__ ei_ab, const int* __restrict__ ei_ba,
            const int* __restrict__ ei_aa, int* __restrict__ deg3)
{
    const int r = blockIdx.y;
    const int* ei = (r == 0) ? ei_ab : (r == 1) ? ei_ba : ei_aa;
    const int e = blockIdx.x * 256 + threadIdx.x;
    if (e < NEDGE) atomicAdd(&deg3[r * NA + ei[NEDGE + e]], 1);
}

__global__ void __launch_bounds__(256)
scan1_kernel(const int* __restrict__ deg, int* __restrict__ bsum, int n)
{
    __shared__ int red[256];
    const int base = blockIdx.x * SCAN_ITEMS + threadIdx.x * 4;
    int s = 0;
#pragma unroll
    for (int j = 0; j < 4; ++j) { const int i = base + j; if (i < n) s += deg[i]; }
    red[threadIdx.x] = s; __syncthreads();
    for (int d = 128; d > 0; d >>= 1) {
        if (threadIdx.x < d) red[threadIdx.x] += red[threadIdx.x + d];
        __syncthreads();
    }
    if (threadIdx.x == 0) bsum[blockIdx.x] = red[0];
}

__global__ void __launch_bounds__(512)
scan2_kernel(const int* __restrict__ bsum, int* __restrict__ bscan, int nblk, int* __restrict__ off_last)
{
    __shared__ int sc[512];
    const int t = threadIdx.x;
    const int v = (t < nblk) ? bsum[t] : 0;
    sc[t] = v; __syncthreads();
    for (int d = 1; d < 512; d <<= 1) {
        const int x = (t >= d) ? sc[t - d] : 0;
        __syncthreads();
        sc[t] += x;
        __syncthreads();
    }
    if (t < nblk) bscan[t] = sc[t] - v;          // exclusive
    if (t == nblk - 1) *off_last = sc[t];        // total = 3*E
}

__global__ void __launch_bounds__(256)
scan3_kernel(const int* __restrict__ deg, const int* __restrict__ bscan,
             int* __restrict__ off, int* __restrict__ cur, int n)
{
    __shared__ int red[256];
    const int t = threadIdx.x;
    const int base = blockIdx.x * SCAN_ITEMS + t * 4;
    int v[4]; int s = 0;
#pragma unroll
    for (int j = 0; j < 4; ++j) { const int i = base + j; v[j] = (i < n) ? deg[i] : 0; s += v[j]; }
    red[t] = s; __syncthreads();
    for (int d = 1; d < 256; d <<= 1) {
        const int x = (t >= d) ? red[t - d] : 0;
        __syncthreads();
        red[t] += x;
        __syncthreads();
    }
    int ex = red[t] - s + bscan[blockIdx.x];
#pragma unroll
    for (int j = 0; j < 4; ++j) {
        const int i = base + j;
        if (i < n) { off[i] = ex; cur[i] = ex; }
        ex += v[j];
    }
}

__global__ void __launch_bounds__(256)
fill3_kernel(const int* __restrict__ ei_ab, const int* __restrict__ ei_ba,
             const int* __restrict__ ei_aa, int* __restrict__ cur3, int* __restrict__ csr3)
{
    const int r = blockIdx.y;
    const int* ei = (r == 0) ? ei_ab : (r == 1) ? ei_ba : ei_aa;
    const int e = blockIdx.x * 256 + threadIdx.x;
    if (e >= NEDGE) return;
    const int pos = atomicAdd(&cur3[r * NA + ei[NEDGE + e]], 1);
    csr3[pos] = ei[e];
}

// ---------------- gather-aggregate for all 3 relations (grid.y = relation) --------
__global__ void __launch_bounds__(256)
gather3_kernel(const ushort_t* __restrict__ h_a, const ushort_t* __restrict__ h_b,
               const int* __restrict__ csr3, const int* __restrict__ off3,
               ushort_t* __restrict__ s_ab, ushort_t* __restrict__ s_ba,
               ushort_t* __restrict__ s_aa)
{
    const int r = blockIdx.y;
    const ushort_t* hsrc = (r == 1) ? h_b : h_a;
    ushort_t* s = (r == 0) ? s_ab : (r == 1) ? s_ba : s_aa;
    const int* off = off3 + r * NA;          // off[NA] = start of next relation = end of this one
    const int wid = threadIdx.x >> 6, lane = threadIdx.x & 63;
    const int nw = gridDim.x * 4;
    for (int node = blockIdx.x * 4 + wid; node < NA; node += nw) {
        const int o0 = off[node], o1 = off[node + 1];
        float ax = 0.f, ay = 0.f;
        int j = o0;
        for (; j + 4 <= o1; j += 4) {
            const int s0 = csr3[j], s1 = csr3[j + 1], s2 = csr3[j + 2], s3 = csr3[j + 3];
            const uint_t v0 = *reinterpret_cast<const uint_t*>(hsrc + (size_t)s0 * HD + 2 * lane);
            const uint_t v1 = *reinterpret_cast<const uint_t*>(hsrc + (size_t)s1 * HD + 2 * lane);
            const uint_t v2 = *reinterpret_cast<const uint_t*>(hsrc + (size_t)s2 * HD + 2 * lane);
            const uint_t v3 = *reinterpret_cast<const uint_t*>(hsrc + (size_t)s3 * HD + 2 * lane);
            ax += bflo(v0) + bflo(v1) + bflo(v2) + bflo(v3);
            ay += bfhi(v0) + bfhi(v1) + bfhi(v2) + bfhi(v3);
        }
        for (; j < o1; ++j) {
            const uint_t v = *reinterpret_cast<const uint_t*>(hsrc + (size_t)csr3[j] * HD + 2 * lane);
            ax += bflo(v); ay += bfhi(v);
        }
        const float inv = 1.0f / fmaxf((float)(o1 - o0), 1.0f);
        *reinterpret_cast<uint_t*>(s + (size_t)node * HD + 2 * lane) = pack2bf(ax * inv, ay * inv);
    }
}

// ---------------- weight prep: W^T, bf16, XOR-swizzled (chunk ^= n&7) ----------------
// m=0: Wl_ab -> wt_fb[0]; m=1: Wr_ab -> wt_fb[1];
// m=2: Wl_ba -> wt_pa[0]; m=3: Wl_aa -> wt_pa[1]; m=4: (Wr_ba+Wr_aa) -> wt_pa[2]
__global__ void __launch_bounds__(256)
prep_w_kernel(const float* __restrict__ Wl_ab, const float* __restrict__ Wr_ab,
              const float* __restrict__ Wl_ba, const float* __restrict__ Wl_aa,
              const float* __restrict__ Wr_ba, const float* __restrict__ Wr_aa,
              ushort_t* __restrict__ wt_fb, ushort_t* __restrict__ wt_pa)
{
    const int m = blockIdx.x >> 3;
    const int id = (blockIdx.x & 7) * 256 + threadIdx.x;   // 0..2047
    const int nn = id >> 4, ck = id & 15;
    const float* src = (m == 0) ? Wl_ab : (m == 1) ? Wr_ab : (m == 2) ? Wl_ba
                     : (m == 3) ? Wl_aa : Wr_ba;
    ushort_t* dst = (m < 2) ? (wt_fb + m * 16384) : (wt_pa + (m - 2) * 16384);
    __align__(16) ushort_t tmp[8];
#pragma unroll
    for (int j = 0; j < 8; ++j) {
        const int k = ck * 8 + j;
        float v = src[k * HD + nn];
        if (m == 4) v += Wr_aa[k * HD + nn];
        tmp[j] = (ushort_t)f2bf(v);
    }
    const int cks = ck ^ (nn & 7);
    *reinterpret_cast<uint4*>(dst + nn * HD + cks * 8) = *reinterpret_cast<const uint4*>(tmp);
}

__global__ void bias_add_kernel(const float* __restrict__ a, const float* __restrict__ b,
                                float* __restrict__ c)
{
    const int i = threadIdx.x;
    if (i < HD) c[i] = a[i] + b[i];
}

// ---------------- MFMA fused GEMM: C = sum_s X_s @ W_s + bias; relu(SC*(C)); pool ----
// SCALE_HALF=0: val = relu(acc+bias); SCALE_HALF=1: val = relu(0.5*(acc+bias))
template<int NSRC, int SCALE_HALF>
__global__ void __launch_bounds__(256)
mfma_fused(const ushort_t* __restrict__ x0, const ushort_t* __restrict__ x1,
           const ushort_t* __restrict__ x2,
           const ushort_t* __restrict__ wts, const float* __restrict__ bias,
           const int* __restrict__ batch, float* __restrict__ outp, int n)
{
    extern __shared__ char smem[];
    ushort_t* wlds   = (ushort_t*)smem;                    // NSRC*16384 bf16 (swizzled W^T)
    float* bias_lds  = (float*)(smem + NSRC * 32768);      // 128 f32
    float* poolbuf   = bias_lds + HD;                      // PG*128 f32

    for (int i = threadIdx.x * 8; i < NSRC * 16384; i += 256 * 8)
        *reinterpret_cast<uint4*>(wlds + i) = *reinterpret_cast<const uint4*>(wts + i);
    if (threadIdx.x < HD) bias_lds[threadIdx.x] = bias ? bias[threadIdx.x] : 0.f;
    for (int i = threadIdx.x; i < PG * HD; i += 256) poolbuf[i] = 0.f;
    __syncthreads();

    const int l  = threadIdx.x & 63, w = threadIdx.x >> 6;
    const int lo = l & 15, hi = l >> 4;
    const int row_base = blockIdx.x * 128 + w * 32;

    f32x4 acc[2][8];
    const f32x4 zero = {0.f, 0.f, 0.f, 0.f};
#pragma unroll
    for (int mi = 0; mi < 2; ++mi)
#pragma unroll
        for (int ni = 0; ni < 8; ++ni) acc[mi][ni] = zero;

#pragma unroll
    for (int s = 0; s < NSRC; ++s) {
        const ushort_t* xs = (s == 0) ? x0 : (s == 1) ? x1 : x2;
        bf16x8 a[2][4];
#pragma unroll
        for (int mi = 0; mi < 2; ++mi) {
            int r = row_base + mi * 16 + lo;
            r = min(r, n - 1);
            const ushort_t* xr = xs + (size_t)r * HD + hi * 8;
#pragma unroll
            for (int kk = 0; kk < 4; ++kk)
                a[mi][kk] = *reinterpret_cast<const bf16x8*>(xr + kk * 32);
        }
        const ushort_t* wb = wlds + s * 16384;
#pragma unroll
        for (int kk = 0; kk < 4; ++kk) {
#pragma unroll
            for (int ni = 0; ni < 8; ++ni) {
                const int nn = ni * 16 + lo;
                const int ck = (kk * 4 + hi) ^ (nn & 7);
                const bf16x8 b = *reinterpret_cast<const bf16x8*>(wb + nn * HD + ck * 8);
                acc[0][ni] = __builtin_amdgcn_mfma_f32_16x16x32_bf16(a[0][kk], b, acc[0][ni], 0, 0, 0);
                acc[1][ni] = __builtin_amdgcn_mfma_f32_16x16x32_bf16(a[1][kk], b, acc[1][ni], 0, 0, 0);
            }
        }
    }

    const int gmin = batch[blockIdx.x * 128];

#pragma unroll
    for (int mi = 0; mi < 2; ++mi) {
#pragma unroll
        for (int ni = 0; ni < 8; ++ni) {
            const int col = ni * 16 + lo;
            const float bv = bias_lds[col];
            const f32x4 v = acc[mi][ni];
#pragma unroll
            for (int r = 0; r < 4; ++r) {
                const int row = row_base + mi * 16 + hi * 4 + r;
                if (row < n) {
                    float val = v[r] + bv;
                    if (SCALE_HALF) val *= 0.5f;
                    val = fmaxf(val, 0.f);
                    const int g = batch[row];
                    const unsigned slot = (unsigned)(g - gmin);
                    if (slot < PG) atomicAdd(&poolbuf[slot * HD + col], val);
                    else unsafeAtomicAdd(outp + (size_t)g * HD + col, val);
                }
            }
        }
    }
    __syncthreads();
    for (int i = threadIdx.x; i < PG * HD; i += 256) {
        const float v = poolbuf[i];
        if (v != 0.f) {
            const int g = gmin + (i >> 7);
            if (g < NG) unsafeAtomicAdd(outp + (size_t)g * HD + (i & 127), v);
        }
    }
}

// ---------------- head: out = (0.5*(pa/ga + pb/gb)) @ Wout + bout ----------------
__global__ void final_kernel(const float* __restrict__ pa, const float* __restrict__ pb,
                             const float* __restrict__ ga, const float* __restrict__ gb,
                             const float* __restrict__ Wout, const float* __restrict__ bout,
                             float* __restrict__ out)
{
    const int g = blockIdx.x;
    const int lane = threadIdx.x;
    const float inva = 1.0f / fmaxf(ga[g], 1.0f);
    const float invb = 1.0f / fmaxf(gb[g], 1.0f);
    if (lane < OUTD) {
        float acc = bout[lane];
        for (int k = 0; k < HD; ++k) {
            const float x = 0.5f * (pa[g * HD + k] * inva + pb[g * HD + k] * invb);
            acc = fmaf(x, Wout[k * OUTD + lane], acc);
        }
        out[g * OUTD + lane] = acc;
    }
}

extern "C" void kernel_launch(void* const* d_in, const int* in_sizes, int n_in,
                              void* d_out, int out_size, void* d_ws, size_t ws_size,
                              hipStream_t stream)
{
    const float* x_a     = (const float*)d_in[0];
    const float* x_b     = (const float*)d_in[1];
    const int*   ei_ab   = (const int*)d_in[2];
    const int*   ei_ba   = (const int*)d_in[3];
    const int*   ei_aa   = (const int*)d_in[4];
    const int*   batch_a = (const int*)d_in[5];
    const int*   batch_b = (const int*)d_in[6];
    const float* Wemb_a  = (const float*)d_in[7];
    const float* bemb_a  = (const float*)d_in[8];
    const float* Wemb_b  = (const float*)d_in[9];
    const float* bemb_b  = (const float*)d_in[10];
    const float* Wl_ab   = (const float*)d_in[11];
    const float* bl_ab   = (const float*)d_in[12];
    const float* Wr_ab   = (const float*)d_in[13];
    const float* Wl_ba   = (const float*)d_in[14];
    const float* bl_ba   = (const float*)d_in[15];
    const float* Wr_ba   = (const float*)d_in[16];
    const float* Wl_aa   = (const float*)d_in[17];
    const float* bl_aa   = (const float*)d_in[18];
    const float* Wr_aa   = (const float*)d_in[19];
    const float* Wout    = (const float*)d_in[20];
    const float* bout    = (const float*)d_in[21];
    float* out = (float*)d_out;

    // ---------------- workspace layout ----------------
    char* p = (char*)d_ws;
    ushort_t* h_a  = (ushort_t*)p; p += (size_t)NA * HD * 2;
    ushort_t* h_b  = (ushort_t*)p; p += (size_t)NB * HD * 2;
    ushort_t* s_ab = (ushort_t*)p; p += (size_t)NB * HD * 2;
    ushort_t* s_ba = (ushort_t*)p; p += (size_t)NA * HD * 2;
    ushort_t* s_aa = (ushort_t*)p; p += (size_t)NA * HD * 2;
    int* csr3 = (int*)p; p += (size_t)3 * NEDGE * 4;           // 19.2 MB
    int* deg3 = (int*)p; p += (size_t)3 * NA * 4;
    int* off3 = (int*)p; p += (size_t)(3 * NA + 4) * 4;
    int* cur3 = (int*)p; p += (size_t)3 * NA * 4;
    int* bsum = (int*)p; p += 512 * 4;
    int* bscan= (int*)p; p += 512 * 4;
    float* pool_a = (float*)p; p += (size_t)NG * HD * 4;
    float* pool_b = (float*)p; p += (size_t)NG * HD * 4;
    float* gcnt_a = (float*)p; p += NG * 4;
    float* gcnt_b = (float*)p; p += NG * 4;
    ushort_t* wt_fb = (ushort_t*)p; p += 2 * 16384 * 2;
    ushort_t* wt_pa = (ushort_t*)p; p += 3 * 16384 * 2;
    float* bias_pa  = (float*)p;    p += HD * 4;

    const int N3 = 3 * NA;
    const int NBLK3 = (N3 + SCAN_ITEMS - 1) / SCAN_ITEMS;      // 293
    const int EGRID = (NEDGE + 255) / 256;                     // 6250
    const int GT = (NA + 127) / 128;                           // 782

    // zero pool accumulators (pool_a, pool_b contiguous) and deg3
    hipMemsetAsync(pool_a, 0, (size_t)2 * NG * HD * 4, stream);
    hipMemsetAsync(deg3, 0, (size_t)N3 * 4, stream);

    prep_w_kernel<<<40, 256, 0, stream>>>(Wl_ab, Wr_ab, Wl_ba, Wl_aa, Wr_ba, Wr_aa,
                                          wt_fb, wt_pa);
    bias_add_kernel<<<1, 128, 0, stream>>>(bl_ba, bl_aa, bias_pa);

    emb_kernel<DA><<<(NA + 3) / 4, 256, 0, stream>>>(x_a, Wemb_a, bemb_a, h_a, NA);
    emb_kernel<DB><<<(NB + 3) / 4, 256, 0, stream>>>(x_b, Wemb_b, bemb_b, h_b, NB);
    gcount_kernel<<<2, 256, 0, stream>>>(batch_a, batch_b, gcnt_a, gcnt_b);

    // ---- merged CSR build (one chain for all 3 relations) ----
    deg3_kernel<<<dim3(EGRID, 3), 256, 0, stream>>>(ei_ab, ei_ba, ei_aa, deg3);
    scan1_kernel<<<NBLK3, 256, 0, stream>>>(deg3, bsum, N3);
    scan2_kernel<<<1, 512, 0, stream>>>(bsum, bscan, NBLK3, off3 + N3);
    scan3_kernel<<<NBLK3, 256, 0, stream>>>(deg3, bscan, off3, cur3, N3);
    fill3_kernel<<<dim3(EGRID, 3), 256, 0, stream>>>(ei_ab, ei_ba, ei_aa, cur3, csr3);
    gather3_kernel<<<dim3(2048, 3), 256, 0, stream>>>(h_a, h_b, csr3, off3, s_ab, s_ba, s_aa);

    // ---- MFMA fused GEMMs ----
    const int lds_fb = 2 * 32768 + 512 + PG * HD * 4;   // 74240
    const int lds_pa = 3 * 32768 + 512 + PG * HD * 4;   // 107008
    hipFuncSetAttribute((const void*)mfma_fused<2, 0>, hipFuncAttributeMaxDynamicSharedMemorySize, lds_fb);
    hipFuncSetAttribute((const void*)mfma_fused<3, 1>, hipFuncAttributeMaxDynamicSharedMemorySize, lds_pa);

    // dst 'b': relu(s_ab@Wl_ab + h_b@Wr_ab + bl_ab) -> pool_b
    mfma_fused<2, 0><<<GT, 256, lds_fb, stream>>>(s_ab, h_b, nullptr, wt_fb, bl_ab, batch_b, pool_b, NB);
    // dst 'a': relu(0.5*(s_ba@Wl_ba + s_aa@Wl_aa + h_a@(Wr_ba+Wr_aa) + bl_ba+bl_aa)) -> pool_a
    mfma_fused<3, 1><<<GT, 256, lds_pa, stream>>>(s_ba, s_aa, h_a, wt_pa, bias_pa, batch_a, pool_a, NA);

    final_kernel<<<NG, 64, 0, stream>>>(pool_a, pool_b, gcnt_a, gcnt_b, Wout, bout, out);
}

// Round 5
// 663.442 us; speedup vs baseline: 14.9079x; 1.7966x over previous
//
#include <hip/hip_runtime.h>

#define NA 100000
#define NB 100000
#define NEDGE 1600000
#define HD 128
#define OUTD 16
#define NG 256
#define DA 64
#define DB 32
#define PG 16

#define BIN_SHIFT 9
#define BIN_W 512
#define NBINS_R 196              // ceil(100000/512)
#define NBINS 588                // 3 relations
#define EPB 8192                 // edges per block in hist/part
#define ECHUNKS 196              // ceil(NEDGE/EPB)

typedef unsigned int uint_t;
typedef unsigned short ushort_t;
typedef __bf16 bf16_t;
typedef bf16_t bf16x8 __attribute__((ext_vector_type(8)));
typedef float f32x4 __attribute__((ext_vector_type(4)));

__device__ __forceinline__ float bflo(uint_t u) {
    union { uint_t i; float f; } c; c.i = u << 16; return c.f;
}
__device__ __forceinline__ float bfhi(uint_t u) {
    union { uint_t i; float f; } c; c.i = u & 0xffff0000u; return c.f;
}
__device__ __forceinline__ uint_t f2bf(float f) {
    union { float f; uint_t i; } c; c.f = f;
    uint_t r = c.i + 0x7FFFu + ((c.i >> 16) & 1u);
    return r >> 16;
}
__device__ __forceinline__ uint_t pack2bf(float lo, float hi) {
    return f2bf(lo) | (f2bf(hi) << 16);
}

// ---------------- input embedding: h = x @ W + b  (K -> 128), bf16 out ----------------
template<int K>
__global__ void __launch_bounds__(256)
emb_kernel(const float* __restrict__ x, const float* __restrict__ W,
           const float* __restrict__ bias, ushort_t* __restrict__ h, int n)
{
    __shared__ float Ws[K * HD];
    __shared__ float bs[HD];
    for (int i = threadIdx.x; i < K * HD; i += 256) Ws[i] = W[i];
    if (threadIdx.x < HD) bs[threadIdx.x] = bias[threadIdx.x];
    __syncthreads();
    const int wid = threadIdx.x >> 6, lane = threadIdx.x & 63;
    const int c0 = 2 * lane;
    for (int row = blockIdx.x * 4 + wid; row < n; row += gridDim.x * 4) {
        const float* xr = x + (size_t)row * K;
        float a0 = bs[c0], a1 = bs[c0 + 1];
#pragma unroll 8
        for (int k = 0; k < K; ++k) {
            const float xv = xr[k];
            const float2 w = *reinterpret_cast<const float2*>(Ws + k * HD + c0);
            a0 = fmaf(xv, w.x, a0);
            a1 = fmaf(xv, w.y, a1);
        }
        *reinterpret_cast<uint_t*>(h + (size_t)row * HD + c0) = pack2bf(a0, a1);
    }
}

// ---------------- per-graph node counts via binary search (batch is sorted) --------
__global__ void __launch_bounds__(256)
gcount_kernel(const int* __restrict__ batch_a, const int* __restrict__ batch_b,
              float* __restrict__ ga, float* __restrict__ gb)
{
    const int g = threadIdx.x;              // 0..255
    const int* batch = blockIdx.x ? batch_b : batch_a;
    float* outp = blockIdx.x ? gb : ga;
    const int n = blockIdx.x ? NB : NA;
    int lo0 = 0, hi0 = n;                   // lower_bound(g)
    while (lo0 < hi0) { const int mid = (lo0 + hi0) >> 1; if (batch[mid] < g) lo0 = mid + 1; else hi0 = mid; }
    int lo1 = 0, hi1 = n;                   // lower_bound(g+1)
    while (lo1 < hi1) { const int mid = (lo1 + hi1) >> 1; if (batch[mid] < g + 1) lo1 = mid + 1; else hi1 = mid; }
    outp[g] = (float)(lo1 - lo0);
}

// ---------------- binned CSR build, pass 1: histogram per bin ----------------
__global__ void __launch_bounds__(256)
hist3_kernel(const int* __restrict__ ei_ab, const int* __restrict__ ei_ba,
             const int* __restrict__ ei_aa, int* __restrict__ binhist)
{
    __shared__ int lh[NBINS_R];
    const int r = blockIdx.y;
    const int* ei = (r == 0) ? ei_ab : (r == 1) ? ei_ba : ei_aa;
    for (int i = threadIdx.x; i < NBINS_R; i += 256) lh[i] = 0;
    __syncthreads();
    const int e0 = blockIdx.x * EPB;
    const int e1 = min(e0 + EPB, NEDGE);
    for (int e = e0 + threadIdx.x; e < e1; e += 256)
        atomicAdd(&lh[ei[NEDGE + e] >> BIN_SHIFT], 1);
    __syncthreads();
    for (int i = threadIdx.x; i < NBINS_R; i += 256)
        if (lh[i]) atomicAdd(&binhist[r * NBINS_R + i], lh[i]);
}

// ---------------- bin scan (1 block, 1024 threads, Hillis-Steele) ----------------
__global__ void __launch_bounds__(1024)
bin_scan_kernel(const int* __restrict__ binhist, int* __restrict__ binscan,
                int* __restrict__ bincur, int* __restrict__ off3_sentinel)
{
    __shared__ int sc[1024];
    const int t = threadIdx.x;
    const int v = (t < NBINS) ? binhist[t] : 0;
    sc[t] = v; __syncthreads();
    for (int d = 1; d < 1024; d <<= 1) {
        const int x = (t >= d) ? sc[t - d] : 0;
        __syncthreads();
        sc[t] += x;
        __syncthreads();
    }
    if (t < NBINS) { const int ex = sc[t] - v; binscan[t] = ex; bincur[t] = ex; }
    if (t == NBINS - 1) {
        binscan[NBINS] = sc[t];              // total = 3*E
        *off3_sentinel = sc[t];
    }
}

// ---------------- pass 2: partition edges into bin-contiguous buffer ----------------
// packed entry: (dst&511)<<17 | src   (src < 2^17)
__global__ void __launch_bounds__(256)
part3_kernel(const int* __restrict__ ei_ab, const int* __restrict__ ei_ba,
             const int* __restrict__ ei_aa, int* __restrict__ bincur,
             uint_t* __restrict__ binned)
{
    __shared__ int lh[NBINS_R];
    __shared__ int lcur[NBINS_R];
    const int r = blockIdx.y;
    const int* ei = (r == 0) ? ei_ab : (r == 1) ? ei_ba : ei_aa;
    for (int i = threadIdx.x; i < NBINS_R; i += 256) lh[i] = 0;
    __syncthreads();
    const int e0 = blockIdx.x * EPB;
    const int e1 = min(e0 + EPB, NEDGE);
    for (int e = e0 + threadIdx.x; e < e1; e += 256)
        atomicAdd(&lh[ei[NEDGE + e] >> BIN_SHIFT], 1);
    __syncthreads();
    for (int i = threadIdx.x; i < NBINS_R; i += 256) {
        const int c = lh[i];
        lcur[i] = c ? atomicAdd(&bincur[r * NBINS_R + i], c) : 0;
    }
    __syncthreads();
    for (int e = e0 + threadIdx.x; e < e1; e += 256) {
        const int dst = ei[NEDGE + e];
        const int src = ei[e];
        const int bin = dst >> BIN_SHIFT;
        const int pos = atomicAdd(&lcur[bin], 1);
        binned[pos] = ((uint_t)(dst & (BIN_W - 1)) << 17) | (uint_t)src;
    }
}

// ---------------- pass 3: per-bin node offsets + csr fill (one block per bin) -----
__global__ void __launch_bounds__(256)
binfill3_kernel(const uint_t* __restrict__ binned, const int* __restrict__ binscan,
                int* __restrict__ off3, int* __restrict__ csr3)
{
    __shared__ int hist[BIN_W];
    __shared__ int A[BIN_W];
    __shared__ int cursor[BIN_W];
    const int b = blockIdx.x;                  // bin within relation
    const int r = blockIdx.y;
    const int g = r * NBINS_R + b;
    const int start = binscan[g], end = binscan[g + 1];
    const int t = threadIdx.x;
    const int i0 = t, i1 = t + 256;
    hist[i0] = 0; hist[i1] = 0;
    __syncthreads();
    for (int j = start + t; j < end; j += 256)
        atomicAdd(&hist[binned[j] >> 17], 1);
    __syncthreads();
    A[i0] = hist[i0]; A[i1] = hist[i1];
    __syncthreads();
    for (int d = 1; d < BIN_W; d <<= 1) {
        const int x0 = (i0 >= d) ? A[i0 - d] : 0;
        const int x1 = (i1 >= d) ? A[i1 - d] : 0;
        __syncthreads();
        A[i0] += x0; A[i1] += x1;
        __syncthreads();
    }
    const int node0 = b * BIN_W;
#pragma unroll
    for (int q = 0; q < 2; ++q) {
        const int i = t + q * 256;
        const int ex = start + A[i] - hist[i];
        cursor[i] = ex;
        const int node = node0 + i;
        if (node < NA) off3[r * NA + node] = ex;
    }
    __syncthreads();
    for (int j = start + t; j < end; j += 256) {
        const uint_t p = binned[j];
        const int pos = atomicAdd(&cursor[p >> 17], 1);
        csr3[pos] = (int)(p & 0x1FFFFu);
    }
}

// ---------------- gather-aggregate for all 3 relations (grid.y = relation) --------
__global__ void __launch_bounds__(256)
gather3_kernel(const ushort_t* __restrict__ h_a, const ushort_t* __restrict__ h_b,
               const int* __restrict__ csr3, const int* __restrict__ off3,
               ushort_t* __restrict__ s_ab, ushort_t* __restrict__ s_ba,
               ushort_t* __restrict__ s_aa)
{
    const int r = blockIdx.y;
    const ushort_t* hsrc = (r == 1) ? h_b : h_a;
    ushort_t* s = (r == 0) ? s_ab : (r == 1) ? s_ba : s_aa;
    const int* off = off3 + r * NA;
    const int wid = threadIdx.x >> 6, lane = threadIdx.x & 63;
    const int nw = gridDim.x * 4;
    for (int node = blockIdx.x * 4 + wid; node < NA; node += nw) {
        const int o0 = off[node], o1 = off[node + 1];
        float ax = 0.f, ay = 0.f;
        int j = o0;
        for (; j + 4 <= o1; j += 4) {
            const int s0 = csr3[j], s1 = csr3[j + 1], s2 = csr3[j + 2], s3 = csr3[j + 3];
            const uint_t v0 = *reinterpret_cast<const uint_t*>(hsrc + (size_t)s0 * HD + 2 * lane);
            const uint_t v1 = *reinterpret_cast<const uint_t*>(hsrc + (size_t)s1 * HD + 2 * lane);
            const uint_t v2 = *reinterpret_cast<const uint_t*>(hsrc + (size_t)s2 * HD + 2 * lane);
            const uint_t v3 = *reinterpret_cast<const uint_t*>(hsrc + (size_t)s3 * HD + 2 * lane);
            ax += bflo(v0) + bflo(v1) + bflo(v2) + bflo(v3);
            ay += bfhi(v0) + bfhi(v1) + bfhi(v2) + bfhi(v3);
        }
        for (; j < o1; ++j) {
            const uint_t v = *reinterpret_cast<const uint_t*>(hsrc + (size_t)csr3[j] * HD + 2 * lane);
            ax += bflo(v); ay += bfhi(v);
        }
        const float inv = 1.0f / fmaxf((float)(o1 - o0), 1.0f);
        *reinterpret_cast<uint_t*>(s + (size_t)node * HD + 2 * lane) = pack2bf(ax * inv, ay * inv);
    }
}

// ---------------- weight prep: W^T, bf16, XOR-swizzled (chunk ^= n&7) ----------------
// m=0: Wl_ab -> wt_fb[0]; m=1: Wr_ab -> wt_fb[1];
// m=2: Wl_ba -> wt_pa[0]; m=3: Wl_aa -> wt_pa[1]; m=4: (Wr_ba+Wr_aa) -> wt_pa[2]
__global__ void __launch_bounds__(256)
prep_w_kernel(const float* __restrict__ Wl_ab, const float* __restrict__ Wr_ab,
              const float* __restrict__ Wl_ba, const float* __restrict__ Wl_aa,
              const float* __restrict__ Wr_ba, const float* __restrict__ Wr_aa,
              ushort_t* __restrict__ wt_fb, ushort_t* __restrict__ wt_pa)
{
    const int m = blockIdx.x >> 3;
    const int id = (blockIdx.x & 7) * 256 + threadIdx.x;   // 0..2047
    const int nn = id >> 4, ck = id & 15;
    const float* src = (m == 0) ? Wl_ab : (m == 1) ? Wr_ab : (m == 2) ? Wl_ba
                     : (m == 3) ? Wl_aa : Wr_ba;
    ushort_t* dst = (m < 2) ? (wt_fb + m * 16384) : (wt_pa + (m - 2) * 16384);
    __align__(16) ushort_t tmp[8];
#pragma unroll
    for (int j = 0; j < 8; ++j) {
        const int k = ck * 8 + j;
        float v = src[k * HD + nn];
        if (m == 4) v += Wr_aa[k * HD + nn];
        tmp[j] = (ushort_t)f2bf(v);
    }
    const int cks = ck ^ (nn & 7);
    *reinterpret_cast<uint4*>(dst + nn * HD + cks * 8) = *reinterpret_cast<const uint4*>(tmp);
}

__global__ void bias_add_kernel(const float* __restrict__ a, const float* __restrict__ b,
                                float* __restrict__ c)
{
    const int i = threadIdx.x;
    if (i < HD) c[i] = a[i] + b[i];
}

// ---------------- MFMA fused GEMM: C = sum_s X_s @ W_s + bias; relu(SC*(C)); pool ----
template<int NSRC, int SCALE_HALF>
__global__ void __launch_bounds__(256)
mfma_fused(const ushort_t* __restrict__ x0, const ushort_t* __restrict__ x1,
           const ushort_t* __restrict__ x2,
           const ushort_t* __restrict__ wts, const float* __restrict__ bias,
           const int* __restrict__ batch, float* __restrict__ outp, int n)
{
    extern __shared__ char smem[];
    ushort_t* wlds   = (ushort_t*)smem;                    // NSRC*16384 bf16 (swizzled W^T)
    float* bias_lds  = (float*)(smem + NSRC * 32768);      // 128 f32
    float* poolbuf   = bias_lds + HD;                      // PG*128 f32

    for (int i = threadIdx.x * 8; i < NSRC * 16384; i += 256 * 8)
        *reinterpret_cast<uint4*>(wlds + i) = *reinterpret_cast<const uint4*>(wts + i);
    if (threadIdx.x < HD) bias_lds[threadIdx.x] = bias ? bias[threadIdx.x] : 0.f;
    for (int i = threadIdx.x; i < PG * HD; i += 256) poolbuf[i] = 0.f;
    __syncthreads();

    const int l  = threadIdx.x & 63, w = threadIdx.x >> 6;
    const int lo = l & 15, hi = l >> 4;
    const int row_base = blockIdx.x * 128 + w * 32;

    f32x4 acc[2][8];
    const f32x4 zero = {0.f, 0.f, 0.f, 0.f};
#pragma unroll
    for (int mi = 0; mi < 2; ++mi)
#pragma unroll
        for (int ni = 0; ni < 8; ++ni) acc[mi][ni] = zero;

#pragma unroll
    for (int s = 0; s < NSRC; ++s) {
        const ushort_t* xs = (s == 0) ? x0 : (s == 1) ? x1 : x2;
        bf16x8 a[2][4];
#pragma unroll
        for (int mi = 0; mi < 2; ++mi) {
            int r = row_base + mi * 16 + lo;
            r = min(r, n - 1);
            const ushort_t* xr = xs + (size_t)r * HD + hi * 8;
#pragma unroll
            for (int kk = 0; kk < 4; ++kk)
                a[mi][kk] = *reinterpret_cast<const bf16x8*>(xr + kk * 32);
        }
        const ushort_t* wb = wlds + s * 16384;
#pragma unroll
        for (int kk = 0; kk < 4; ++kk) {
#pragma unroll
            for (int ni = 0; ni < 8; ++ni) {
                const int nn = ni * 16 + lo;
                const int ck = (kk * 4 + hi) ^ (nn & 7);
                const bf16x8 b = *reinterpret_cast<const bf16x8*>(wb + nn * HD + ck * 8);
                acc[0][ni] = __builtin_amdgcn_mfma_f32_16x16x32_bf16(a[0][kk], b, acc[0][ni], 0, 0, 0);
                acc[1][ni] = __builtin_amdgcn_mfma_f32_16x16x32_bf16(a[1][kk], b, acc[1][ni], 0, 0, 0);
            }
        }
    }

    const int gmin = batch[blockIdx.x * 128];

#pragma unroll
    for (int mi = 0; mi < 2; ++mi) {
#pragma unroll
        for (int ni = 0; ni < 8; ++ni) {
            const int col = ni * 16 + lo;
            const float bv = bias_lds[col];
            const f32x4 v = acc[mi][ni];
#pragma unroll
            for (int r = 0; r < 4; ++r) {
                const int row = row_base + mi * 16 + hi * 4 + r;
                if (row < n) {
                    float val = v[r] + bv;
                    if (SCALE_HALF) val *= 0.5f;
                    val = fmaxf(val, 0.f);
                    const int g = batch[row];
                    const unsigned slot = (unsigned)(g - gmin);
                    if (slot < PG) atomicAdd(&poolbuf[slot * HD + col], val);
                    else unsafeAtomicAdd(outp + (size_t)g * HD + col, val);
                }
            }
        }
    }
    __syncthreads();
    for (int i = threadIdx.x; i < PG * HD; i += 256) {
        const float v = poolbuf[i];
        if (v != 0.f) {
            const int g = gmin + (i >> 7);
            if (g < NG) unsafeAtomicAdd(outp + (size_t)g * HD + (i & 127), v);
        }
    }
}

// ---------------- head: out = (0.5*(pa/ga + pb/gb)) @ Wout + bout ----------------
__global__ void final_kernel(const float* __restrict__ pa, const float* __restrict__ pb,
                             const float* __restrict__ ga, const float* __restrict__ gb,
                             const float* __restrict__ Wout, const float* __restrict__ bout,
                             float* __restrict__ out)
{
    const int g = blockIdx.x;
    const int lane = threadIdx.x;
    const float inva = 1.0f / fmaxf(ga[g], 1.0f);
    const float invb = 1.0f / fmaxf(gb[g], 1.0f);
    if (lane < OUTD) {
        float acc = bout[lane];
        for (int k = 0; k < HD; ++k) {
            const float x = 0.5f * (pa[g * HD + k] * inva + pb[g * HD + k] * invb);
            acc = fmaf(x, Wout[k * OUTD + lane], acc);
        }
        out[g * OUTD + lane] = acc;
    }
}

extern "C" void kernel_launch(void* const* d_in, const int* in_sizes, int n_in,
                              void* d_out, int out_size, void* d_ws, size_t ws_size,
                              hipStream_t stream)
{
    const float* x_a     = (const float*)d_in[0];
    const float* x_b     = (const float*)d_in[1];
    const int*   ei_ab   = (const int*)d_in[2];
    const int*   ei_ba   = (const int*)d_in[3];
    const int*   ei_aa   = (const int*)d_in[4];
    const int*   batch_a = (const int*)d_in[5];
    const int*   batch_b = (const int*)d_in[6];
    const float* Wemb_a  = (const float*)d_in[7];
    const float* bemb_a  = (const float*)d_in[8];
    const float* Wemb_b  = (const float*)d_in[9];
    const float* bemb_b  = (const float*)d_in[10];
    const float* Wl_ab   = (const float*)d_in[11];
    const float* bl_ab   = (const float*)d_in[12];
    const float* Wr_ab   = (const float*)d_in[13];
    const float* Wl_ba   = (const float*)d_in[14];
    const float* bl_ba   = (const float*)d_in[15];
    const float* Wr_ba   = (const float*)d_in[16];
    const float* Wl_aa   = (const float*)d_in[17];
    const float* bl_aa   = (const float*)d_in[18];
    const float* Wr_aa   = (const float*)d_in[19];
    const float* Wout    = (const float*)d_in[20];
    const float* bout    = (const float*)d_in[21];
    float* out = (float*)d_out;

    // ---------------- workspace layout ----------------
    char* p = (char*)d_ws;
    ushort_t* h_a  = (ushort_t*)p; p += (size_t)NA * HD * 2;
    ushort_t* h_b  = (ushort_t*)p; p += (size_t)NB * HD * 2;
    ushort_t* s_ab = (ushort_t*)p; p += (size_t)NB * HD * 2;
    ushort_t* s_ba = (ushort_t*)p; p += (size_t)NA * HD * 2;
    ushort_t* s_aa = (ushort_t*)p; p += (size_t)NA * HD * 2;
    int* csr3   = (int*)p;  p += (size_t)3 * NEDGE * 4;        // 19.2 MB
    uint_t* binned = (uint_t*)p; p += (size_t)3 * NEDGE * 4;   // 19.2 MB
    int* off3   = (int*)p;  p += (size_t)(3 * NA + 4) * 4;
    int* binhist= (int*)p;  p += (NBINS + 4) * 4;
    int* binscan= (int*)p;  p += (NBINS + 4) * 4;
    int* bincur = (int*)p;  p += (NBINS + 4) * 4;
    float* pool_a = (float*)p; p += (size_t)NG * HD * 4;
    float* pool_b = (float*)p; p += (size_t)NG * HD * 4;
    float* gcnt_a = (float*)p; p += NG * 4;
    float* gcnt_b = (float*)p; p += NG * 4;
    ushort_t* wt_fb = (ushort_t*)p; p += 2 * 16384 * 2;
    ushort_t* wt_pa = (ushort_t*)p; p += 3 * 16384 * 2;
    float* bias_pa  = (float*)p;    p += HD * 4;

    const int N3 = 3 * NA;
    const int GT = (NA + 127) / 128;                           // 782

    // zero pool accumulators (pool_a, pool_b contiguous) and bin histogram
    hipMemsetAsync(pool_a, 0, (size_t)2 * NG * HD * 4, stream);
    hipMemsetAsync(binhist, 0, (size_t)NBINS * 4, stream);

    prep_w_kernel<<<40, 256, 0, stream>>>(Wl_ab, Wr_ab, Wl_ba, Wl_aa, Wr_ba, Wr_aa,
                                          wt_fb, wt_pa);
    bias_add_kernel<<<1, 128, 0, stream>>>(bl_ba, bl_aa, bias_pa);

    emb_kernel<DA><<<2048, 256, 0, stream>>>(x_a, Wemb_a, bemb_a, h_a, NA);
    emb_kernel<DB><<<2048, 256, 0, stream>>>(x_b, Wemb_b, bemb_b, h_b, NB);
    gcount_kernel<<<2, 256, 0, stream>>>(batch_a, batch_b, gcnt_a, gcnt_b);

    // ---- binned CSR build (no random atomics to large arrays) ----
    hist3_kernel<<<dim3(ECHUNKS, 3), 256, 0, stream>>>(ei_ab, ei_ba, ei_aa, binhist);
    bin_scan_kernel<<<1, 1024, 0, stream>>>(binhist, binscan, bincur, off3 + N3);
    part3_kernel<<<dim3(ECHUNKS, 3), 256, 0, stream>>>(ei_ab, ei_ba, ei_aa, bincur, binned);
    binfill3_kernel<<<dim3(NBINS_R, 3), 256, 0, stream>>>(binned, binscan, off3, csr3);

    gather3_kernel<<<dim3(2048, 3), 256, 0, stream>>>(h_a, h_b, csr3, off3, s_ab, s_ba, s_aa);

    // ---- MFMA fused GEMMs ----
    const int lds_fb = 2 * 32768 + 512 + PG * HD * 4;   // 74240
    const int lds_pa = 3 * 32768 + 512 + PG * HD * 4;   // 107008
    hipFuncSetAttribute((const void*)mfma_fused<2, 0>, hipFuncAttributeMaxDynamicSharedMemorySize, lds_fb);
    hipFuncSetAttribute((const void*)mfma_fused<3, 1>, hipFuncAttributeMaxDynamicSharedMemorySize, lds_pa);

    // dst 'b': relu(s_ab@Wl_ab + h_b@Wr_ab + bl_ab) -> pool_b
    mfma_fused<2, 0><<<GT, 256, lds_fb, stream>>>(s_ab, h_b, nullptr, wt_fb, bl_ab, batch_b, pool_b, NB);
    // dst 'a': relu(0.5*(s_ba@Wl_ba + s_aa@Wl_aa + h_a@(Wr_ba+Wr_aa) + bl_ba+bl_aa)) -> pool_a
    mfma_fused<3, 1><<<GT, 256, lds_pa, stream>>>(s_ba, s_aa, h_a, wt_pa, bias_pa, batch_a, pool_a, NA);

    final_kernel<<<NG, 64, 0, stream>>>(pool_a, pool_b, gcnt_a, gcnt_b, Wout, bout, out);
}

// Round 6
// 594.812 us; speedup vs baseline: 16.6280x; 1.1154x over previous
//
#include <hip/hip_runtime.h>

#define NA 100000
#define NB 100000
#define NEDGE 1600000
#define HD 128
#define OUTD 16
#define NG 256
#define DA 64
#define DB 32
#define PG 8

#define BIN_SHIFT 9
#define BIN_W 512
#define NBINS_R 196              // ceil(100000/512)
#define NBINS 588                // 3 relations
#define EPB 8192                 // edges per block in hist/part
#define ECHUNKS 196              // ceil(NEDGE/EPB)

typedef unsigned int uint_t;
typedef unsigned short ushort_t;
typedef __bf16 bf16_t;
typedef bf16_t bf16x8 __attribute__((ext_vector_type(8)));
typedef float f32x4 __attribute__((ext_vector_type(4)));

__device__ __forceinline__ float bflo(uint_t u) {
    union { uint_t i; float f; } c; c.i = u << 16; return c.f;
}
__device__ __forceinline__ float bfhi(uint_t u) {
    union { uint_t i; float f; } c; c.i = u & 0xffff0000u; return c.f;
}
__device__ __forceinline__ uint_t f2bf(float f) {
    union { float f; uint_t i; } c; c.f = f;
    uint_t r = c.i + 0x7FFFu + ((c.i >> 16) & 1u);
    return r >> 16;
}
__device__ __forceinline__ uint_t pack2bf(float lo, float hi) {
    return f2bf(lo) | (f2bf(hi) << 16);
}

// ---------------- input embedding: h = x @ W + b  (K -> 128), bf16 out ----------------
template<int K>
__global__ void __launch_bounds__(256)
emb_kernel(const float* __restrict__ x, const float* __restrict__ W,
           const float* __restrict__ bias, ushort_t* __restrict__ h, int n)
{
    __shared__ float Ws[K * HD];
    __shared__ float bs[HD];
    for (int i = threadIdx.x; i < K * HD; i += 256) Ws[i] = W[i];
    if (threadIdx.x < HD) bs[threadIdx.x] = bias[threadIdx.x];
    __syncthreads();
    const int wid = threadIdx.x >> 6, lane = threadIdx.x & 63;
    const int c0 = 2 * lane;
    for (int row = blockIdx.x * 4 + wid; row < n; row += gridDim.x * 4) {
        const float* xr = x + (size_t)row * K;
        float a0 = bs[c0], a1 = bs[c0 + 1];
#pragma unroll 8
        for (int k = 0; k < K; ++k) {
            const float xv = xr[k];
            const float2 w = *reinterpret_cast<const float2*>(Ws + k * HD + c0);
            a0 = fmaf(xv, w.x, a0);
            a1 = fmaf(xv, w.y, a1);
        }
        *reinterpret_cast<uint_t*>(h + (size_t)row * HD + c0) = pack2bf(a0, a1);
    }
}

// ---------------- per-graph node counts via binary search (batch is sorted) --------
__global__ void __launch_bounds__(256)
gcount_kernel(const int* __restrict__ batch_a, const int* __restrict__ batch_b,
              float* __restrict__ ga, float* __restrict__ gb)
{
    const int g = threadIdx.x;              // 0..255
    const int* batch = blockIdx.x ? batch_b : batch_a;
    float* outp = blockIdx.x ? gb : ga;
    const int n = blockIdx.x ? NB : NA;
    int lo0 = 0, hi0 = n;                   // lower_bound(g)
    while (lo0 < hi0) { const int mid = (lo0 + hi0) >> 1; if (batch[mid] < g) lo0 = mid + 1; else hi0 = mid; }
    int lo1 = 0, hi1 = n;                   // lower_bound(g+1)
    while (lo1 < hi1) { const int mid = (lo1 + hi1) >> 1; if (batch[mid] < g + 1) lo1 = mid + 1; else hi1 = mid; }
    outp[g] = (float)(lo1 - lo0);
}

// ---------------- binned CSR build, pass 1: histogram per bin ----------------
__global__ void __launch_bounds__(256)
hist3_kernel(const int* __restrict__ ei_ab, const int* __restrict__ ei_ba,
             const int* __restrict__ ei_aa, int* __restrict__ binhist)
{
    __shared__ int lh[NBINS_R];
    const int r = blockIdx.y;
    const int* ei = (r == 0) ? ei_ab : (r == 1) ? ei_ba : ei_aa;
    for (int i = threadIdx.x; i < NBINS_R; i += 256) lh[i] = 0;
    __syncthreads();
    const int e0 = blockIdx.x * EPB;
    const int e1 = min(e0 + EPB, NEDGE);
    for (int e = e0 + threadIdx.x; e < e1; e += 256)
        atomicAdd(&lh[ei[NEDGE + e] >> BIN_SHIFT], 1);
    __syncthreads();
    for (int i = threadIdx.x; i < NBINS_R; i += 256)
        if (lh[i]) atomicAdd(&binhist[r * NBINS_R + i], lh[i]);
}

// ---------------- bin scan (1 block, 1024 threads, Hillis-Steele) ----------------
__global__ void __launch_bounds__(1024)
bin_scan_kernel(const int* __restrict__ binhist, int* __restrict__ binscan,
                int* __restrict__ bincur, int* __restrict__ off3_sentinel)
{
    __shared__ int sc[1024];
    const int t = threadIdx.x;
    const int v = (t < NBINS) ? binhist[t] : 0;
    sc[t] = v; __syncthreads();
    for (int d = 1; d < 1024; d <<= 1) {
        const int x = (t >= d) ? sc[t - d] : 0;
        __syncthreads();
        sc[t] += x;
        __syncthreads();
    }
    if (t < NBINS) { const int ex = sc[t] - v; binscan[t] = ex; bincur[t] = ex; }
    if (t == NBINS - 1) {
        binscan[NBINS] = sc[t];              // total = 3*E
        *off3_sentinel = sc[t];
    }
}

// ---------------- pass 2: partition via LDS-staged sort + coalesced run copy-out ---
// packed entry: (dst&511)<<17 | src   (src < 2^17)
__global__ void __launch_bounds__(256)
part3_kernel(const int* __restrict__ ei_ab, const int* __restrict__ ei_ba,
             const int* __restrict__ ei_aa, int* __restrict__ bincur,
             uint_t* __restrict__ binned)
{
    __shared__ uint_t sorted[EPB];         // 32 KB
    __shared__ int lh[NBINS_R];
    __shared__ int lbase[NBINS_R];
    __shared__ int gbase[NBINS_R];
    __shared__ int lcur[NBINS_R];
    __shared__ int sc[256];
    const int r = blockIdx.y;
    const int* ei = (r == 0) ? ei_ab : (r == 1) ? ei_ba : ei_aa;
    const int t = threadIdx.x;
    for (int i = t; i < NBINS_R; i += 256) lh[i] = 0;
    __syncthreads();
    const int e0 = blockIdx.x * EPB;
    const int e1 = min(e0 + EPB, NEDGE);
    for (int e = e0 + t; e < e1; e += 256)
        atomicAdd(&lh[ei[NEDGE + e] >> BIN_SHIFT], 1);
    __syncthreads();
    // exclusive scan of lh (NBINS_R <= 256)
    {
        const int v = (t < NBINS_R) ? lh[t] : 0;
        sc[t] = v; __syncthreads();
        for (int d = 1; d < 256; d <<= 1) {
            const int x = (t >= d) ? sc[t - d] : 0;
            __syncthreads();
            sc[t] += x;
            __syncthreads();
        }
        if (t < NBINS_R) {
            const int ex = sc[t] - v;
            lbase[t] = ex; lcur[t] = ex;
            gbase[t] = v ? atomicAdd(&bincur[r * NBINS_R + t], v) : 0;
        }
    }
    __syncthreads();
    // scatter into LDS (bin-sorted)
    for (int e = e0 + t; e < e1; e += 256) {
        const int dst = ei[NEDGE + e];
        const int src = ei[e];
        const int bin = dst >> BIN_SHIFT;
        const int pos = atomicAdd(&lcur[bin], 1);
        sorted[pos] = ((uint_t)(dst & (BIN_W - 1)) << 17) | (uint_t)src;
    }
    __syncthreads();
    // coalesced copy-out: one wave per bin-run
    const int wid = t >> 6, lane = t & 63;
    for (int b = wid; b < NBINS_R; b += 4) {
        const int cnt = lh[b], lb = lbase[b], gb = gbase[b];
        for (int k = lane; k < cnt; k += 64) binned[gb + k] = sorted[lb + k];
    }
}

// ---------------- pass 3: per-bin node offsets + csr fill (one block per bin) -----
__global__ void __launch_bounds__(256)
binfill3_kernel(const uint_t* __restrict__ binned, const int* __restrict__ binscan,
                int* __restrict__ off3, int* __restrict__ csr3)
{
    __shared__ int hist[BIN_W];
    __shared__ int A[BIN_W];
    __shared__ int cursor[BIN_W];
    const int b = blockIdx.x;                  // bin within relation
    const int r = blockIdx.y;
    const int g = r * NBINS_R + b;
    const int start = binscan[g], end = binscan[g + 1];
    const int t = threadIdx.x;
    const int i0 = t, i1 = t + 256;
    hist[i0] = 0; hist[i1] = 0;
    __syncthreads();
    for (int j = start + t; j < end; j += 256)
        atomicAdd(&hist[binned[j] >> 17], 1);
    __syncthreads();
    A[i0] = hist[i0]; A[i1] = hist[i1];
    __syncthreads();
    for (int d = 1; d < BIN_W; d <<= 1) {
        const int x0 = (i0 >= d) ? A[i0 - d] : 0;
        const int x1 = (i1 >= d) ? A[i1 - d] : 0;
        __syncthreads();
        A[i0] += x0; A[i1] += x1;
        __syncthreads();
    }
    const int node0 = b * BIN_W;
#pragma unroll
    for (int q = 0; q < 2; ++q) {
        const int i = t + q * 256;
        const int ex = start + A[i] - hist[i];
        cursor[i] = ex;
        const int node = node0 + i;
        if (node < NA) off3[r * NA + node] = ex;
    }
    __syncthreads();
    for (int j = start + t; j < end; j += 256) {
        const uint_t p = binned[j];
        const int pos = atomicAdd(&cursor[p >> 17], 1);
        csr3[pos] = (int)(p & 0x1FFFFu);
    }
}

// ---------------- gather-aggregate, half-wave-paired edges (grid.y = relation) ----
__global__ void __launch_bounds__(256)
gather3_kernel(const ushort_t* __restrict__ h_a, const ushort_t* __restrict__ h_b,
               const int* __restrict__ csr3, const int* __restrict__ off3,
               ushort_t* __restrict__ s_ab, ushort_t* __restrict__ s_ba,
               ushort_t* __restrict__ s_aa)
{
    const int r = blockIdx.y;
    const ushort_t* hsrc = (r == 1) ? h_b : h_a;
    ushort_t* s = (r == 0) ? s_ab : (r == 1) ? s_ba : s_aa;
    const int* off = off3 + r * NA;
    const int wid = threadIdx.x >> 6, lane = threadIdx.x & 63;
    const int hl = lane & 31;               // half-lane: covers cols 4*hl .. 4*hl+3
    const int nw = gridDim.x * 4;
    for (int node = blockIdx.x * 4 + wid; node < NA; node += nw) {
        const int o0 = off[node], o1 = off[node + 1];
        float ax0 = 0.f, ax1 = 0.f, ax2 = 0.f, ax3 = 0.f;
        int j = o0;
        // 2 pairs (4 edges) per iteration: half-wave A = edges j/j+2, B = j+1/j+3
        for (; j + 4 <= o1; j += 4) {
            const int s0 = csr3[j], s1 = csr3[j + 1], s2 = csr3[j + 2], s3 = csr3[j + 3];
            const int sA = (lane & 32) ? s1 : s0;
            const int sB = (lane & 32) ? s3 : s2;
            const uint2 vA = *reinterpret_cast<const uint2*>(hsrc + (size_t)sA * HD + hl * 4);
            const uint2 vB = *reinterpret_cast<const uint2*>(hsrc + (size_t)sB * HD + hl * 4);
            ax0 += bflo(vA.x) + bflo(vB.x); ax1 += bfhi(vA.x) + bfhi(vB.x);
            ax2 += bflo(vA.y) + bflo(vB.y); ax3 += bfhi(vA.y) + bfhi(vB.y);
        }
        for (; j + 2 <= o1; j += 2) {
            const int s0 = csr3[j], s1 = csr3[j + 1];
            const int sA = (lane & 32) ? s1 : s0;
            const uint2 vA = *reinterpret_cast<const uint2*>(hsrc + (size_t)sA * HD + hl * 4);
            ax0 += bflo(vA.x); ax1 += bfhi(vA.x); ax2 += bflo(vA.y); ax3 += bfhi(vA.y);
        }
        if (j < o1) {
            const int s0 = csr3[j];
            const uint2 vA = *reinterpret_cast<const uint2*>(hsrc + (size_t)s0 * HD + hl * 4);
            if (!(lane & 32)) {
                ax0 += bflo(vA.x); ax1 += bfhi(vA.x); ax2 += bflo(vA.y); ax3 += bfhi(vA.y);
            }
        }
        // cross-half reduction (lane ^ 32)
        ax0 += __shfl_xor(ax0, 32); ax1 += __shfl_xor(ax1, 32);
        ax2 += __shfl_xor(ax2, 32); ax3 += __shfl_xor(ax3, 32);
        if (!(lane & 32)) {
            const float inv = 1.0f / fmaxf((float)(o1 - o0), 1.0f);
            uint2 w;
            w.x = pack2bf(ax0 * inv, ax1 * inv);
            w.y = pack2bf(ax2 * inv, ax3 * inv);
            *reinterpret_cast<uint2*>(s + (size_t)node * HD + hl * 4) = w;
        }
    }
}

// ---------------- weight prep: W^T, bf16, XOR-swizzled, col-half-major layout -----
// layout per buffer: [half][matrix][64 rows][128 k], row = out-col (nn)
// m=0: Wl_ab -> wt_fb m0; m=1: Wr_ab -> wt_fb m1;
// m=2: Wl_ba; m=3: Wl_aa; m=4: (Wr_ba+Wr_aa) -> wt_pa m0..m2
__global__ void __launch_bounds__(256)
prep_w_kernel(const float* __restrict__ Wl_ab, const float* __restrict__ Wr_ab,
              const float* __restrict__ Wl_ba, const float* __restrict__ Wl_aa,
              const float* __restrict__ Wr_ba, const float* __restrict__ Wr_aa,
              ushort_t* __restrict__ wt_fb, ushort_t* __restrict__ wt_pa)
{
    const int m = blockIdx.x >> 3;
    const int id = (blockIdx.x & 7) * 256 + threadIdx.x;   // 0..2047
    const int nn = id >> 4, ck = id & 15;
    const float* src = (m == 0) ? Wl_ab : (m == 1) ? Wr_ab : (m == 2) ? Wl_ba
                     : (m == 3) ? Wl_aa : Wr_ba;
    __align__(16) ushort_t tmp[8];
#pragma unroll
    for (int j = 0; j < 8; ++j) {
        const int k = ck * 8 + j;
        float v = src[k * HD + nn];
        if (m == 4) v += Wr_aa[k * HD + nn];
        tmp[j] = (ushort_t)f2bf(v);
    }
    const int cks = ck ^ (nn & 7);
    const int half = nn >> 6, nl = nn & 63;
    ushort_t* dst = (m < 2) ? (wt_fb + half * 16384 + m * 8192)
                            : (wt_pa + half * 24576 + (m - 2) * 8192);
    *reinterpret_cast<uint4*>(dst + nl * HD + cks * 8) = *reinterpret_cast<const uint4*>(tmp);
}

__global__ void bias_add_kernel(const float* __restrict__ a, const float* __restrict__ b,
                                float* __restrict__ c)
{
    const int i = threadIdx.x;
    if (i < HD) c[i] = a[i] + b[i];
}

// ---------------- MFMA fused GEMM, col-split (blockIdx.y = output half) -----------
// C[:, half*64:(half+1)*64] = sum_s X_s @ W_s + bias; relu(opt 0.5*); pool atomics
template<int NSRC, int SCALE_HALF>
__global__ void __launch_bounds__(256)
mfma_fused(const ushort_t* __restrict__ x0, const ushort_t* __restrict__ x1,
           const ushort_t* __restrict__ x2,
           const ushort_t* __restrict__ wts, const float* __restrict__ bias,
           const int* __restrict__ batch, float* __restrict__ outp, int n)
{
    const int half = blockIdx.y;
    extern __shared__ char smem[];
    ushort_t* wlds   = (ushort_t*)smem;                    // NSRC*8192 bf16 (swizzled W^T half)
    float* bias_lds  = (float*)(smem + NSRC * 16384);      // 64 f32
    float* poolbuf   = bias_lds + 64;                      // PG*64 f32

    const ushort_t* wsrc = wts + (size_t)half * NSRC * 8192;
    for (int i = threadIdx.x * 8; i < NSRC * 8192; i += 256 * 8)
        *reinterpret_cast<uint4*>(wlds + i) = *reinterpret_cast<const uint4*>(wsrc + i);
    if (threadIdx.x < 64) bias_lds[threadIdx.x] = bias ? bias[half * 64 + threadIdx.x] : 0.f;
    for (int i = threadIdx.x; i < PG * 64; i += 256) poolbuf[i] = 0.f;
    __syncthreads();

    const int l  = threadIdx.x & 63, w = threadIdx.x >> 6;
    const int lo = l & 15, hi = l >> 4;
    const int row_base = blockIdx.x * 128 + w * 32;

    f32x4 acc[2][4];
    const f32x4 zero = {0.f, 0.f, 0.f, 0.f};
#pragma unroll
    for (int mi = 0; mi < 2; ++mi)
#pragma unroll
        for (int ni = 0; ni < 4; ++ni) acc[mi][ni] = zero;

#pragma unroll
    for (int s = 0; s < NSRC; ++s) {
        const ushort_t* xs = (s == 0) ? x0 : (s == 1) ? x1 : x2;
        bf16x8 a[2][4];
#pragma unroll
        for (int mi = 0; mi < 2; ++mi) {
            int r = row_base + mi * 16 + lo;
            r = min(r, n - 1);
            const ushort_t* xr = xs + (size_t)r * HD + hi * 8;
#pragma unroll
            for (int kk = 0; kk < 4; ++kk)
                a[mi][kk] = *reinterpret_cast<const bf16x8*>(xr + kk * 32);
        }
        const ushort_t* wb = wlds + s * 8192;
#pragma unroll
        for (int kk = 0; kk < 4; ++kk) {
#pragma unroll
            for (int ni = 0; ni < 4; ++ni) {
                const int nn = ni * 16 + lo;
                const int ck = (kk * 4 + hi) ^ (nn & 7);
                const bf16x8 b = *reinterpret_cast<const bf16x8*>(wb + nn * HD + ck * 8);
                acc[0][ni] = __builtin_amdgcn_mfma_f32_16x16x32_bf16(a[0][kk], b, acc[0][ni], 0, 0, 0);
                acc[1][ni] = __builtin_amdgcn_mfma_f32_16x16x32_bf16(a[1][kk], b, acc[1][ni], 0, 0, 0);
            }
        }
    }

    const int gmin = batch[blockIdx.x * 128];

#pragma unroll
    for (int mi = 0; mi < 2; ++mi) {
#pragma unroll
        for (int ni = 0; ni < 4; ++ni) {
            const int col_l = ni * 16 + lo;
            const int col = half * 64 + col_l;
            const float bv = bias_lds[col_l];
            const f32x4 v = acc[mi][ni];
#pragma unroll
            for (int r = 0; r < 4; ++r) {
                const int row = row_base + mi * 16 + hi * 4 + r;
                if (row < n) {
                    float val = v[r] + bv;
                    if (SCALE_HALF) val *= 0.5f;
                    val = fmaxf(val, 0.f);
                    const int g = batch[row];
                    const unsigned slot = (unsigned)(g - gmin);
                    if (slot < PG) atomicAdd(&poolbuf[slot * 64 + col_l], val);
                    else unsafeAtomicAdd(outp + (size_t)g * HD + col, val);
                }
            }
        }
    }
    __syncthreads();
    for (int i = threadIdx.x; i < PG * 64; i += 256) {
        const float v = poolbuf[i];
        if (v != 0.f) {
            const int g = gmin + (i >> 6);
            if (g < NG) unsafeAtomicAdd(outp + (size_t)g * HD + half * 64 + (i & 63), v);
        }
    }
}

// ---------------- head: out = (0.5*(pa/ga + pb/gb)) @ Wout + bout ----------------
__global__ void final_kernel(const float* __restrict__ pa, const float* __restrict__ pb,
                             const float* __restrict__ ga, const float* __restrict__ gb,
                             const float* __restrict__ Wout, const float* __restrict__ bout,
                             float* __restrict__ out)
{
    const int g = blockIdx.x;
    const int lane = threadIdx.x;
    const float inva = 1.0f / fmaxf(ga[g], 1.0f);
    const float invb = 1.0f / fmaxf(gb[g], 1.0f);
    if (lane < OUTD) {
        float acc = bout[lane];
        for (int k = 0; k < HD; ++k) {
            const float x = 0.5f * (pa[g * HD + k] * inva + pb[g * HD + k] * invb);
            acc = fmaf(x, Wout[k * OUTD + lane], acc);
        }
        out[g * OUTD + lane] = acc;
    }
}

extern "C" void kernel_launch(void* const* d_in, const int* in_sizes, int n_in,
                              void* d_out, int out_size, void* d_ws, size_t ws_size,
                              hipStream_t stream)
{
    const float* x_a     = (const float*)d_in[0];
    const float* x_b     = (const float*)d_in[1];
    const int*   ei_ab   = (const int*)d_in[2];
    const int*   ei_ba   = (const int*)d_in[3];
    const int*   ei_aa   = (const int*)d_in[4];
    const int*   batch_a = (const int*)d_in[5];
    const int*   batch_b = (const int*)d_in[6];
    const float* Wemb_a  = (const float*)d_in[7];
    const float* bemb_a  = (const float*)d_in[8];
    const float* Wemb_b  = (const float*)d_in[9];
    const float* bemb_b  = (const float*)d_in[10];
    const float* Wl_ab   = (const float*)d_in[11];
    const float* bl_ab   = (const float*)d_in[12];
    const float* Wr_ab   = (const float*)d_in[13];
    const float* Wl_ba   = (const float*)d_in[14];
    const float* bl_ba   = (const float*)d_in[15];
    const float* Wr_ba   = (const float*)d_in[16];
    const float* Wl_aa   = (const float*)d_in[17];
    const float* bl_aa   = (const float*)d_in[18];
    const float* Wr_aa   = (const float*)d_in[19];
    const float* Wout    = (const float*)d_in[20];
    const float* bout    = (const float*)d_in[21];
    float* out = (float*)d_out;

    // ---------------- workspace layout ----------------
    char* p = (char*)d_ws;
    ushort_t* h_a  = (ushort_t*)p; p += (size_t)NA * HD * 2;
    ushort_t* h_b  = (ushort_t*)p; p += (size_t)NB * HD * 2;
    ushort_t* s_ab = (ushort_t*)p; p += (size_t)NB * HD * 2;
    ushort_t* s_ba = (ushort_t*)p; p += (size_t)NA * HD * 2;
    ushort_t* s_aa = (ushort_t*)p; p += (size_t)NA * HD * 2;
    int* csr3   = (int*)p;  p += (size_t)3 * NEDGE * 4;        // 19.2 MB
    uint_t* binned = (uint_t*)p; p += (size_t)3 * NEDGE * 4;   // 19.2 MB
    int* off3   = (int*)p;  p += (size_t)(3 * NA + 4) * 4;
    int* binhist= (int*)p;  p += (NBINS + 4) * 4;
    int* binscan= (int*)p;  p += (NBINS + 4) * 4;
    int* bincur = (int*)p;  p += (NBINS + 4) * 4;
    float* pool_a = (float*)p; p += (size_t)NG * HD * 4;
    float* pool_b = (float*)p; p += (size_t)NG * HD * 4;
    float* gcnt_a = (float*)p; p += NG * 4;
    float* gcnt_b = (float*)p; p += NG * 4;
    ushort_t* wt_fb = (ushort_t*)p; p += 2 * 16384 * 2;
    ushort_t* wt_pa = (ushort_t*)p; p += 3 * 16384 * 2;
    float* bias_pa  = (float*)p;    p += HD * 4;

    const int N3 = 3 * NA;
    const int GT = (NA + 127) / 128;                           // 782

    // zero pool accumulators (pool_a, pool_b contiguous) and bin histogram
    hipMemsetAsync(pool_a, 0, (size_t)2 * NG * HD * 4, stream);
    hipMemsetAsync(binhist, 0, (size_t)NBINS * 4, stream);

    prep_w_kernel<<<40, 256, 0, stream>>>(Wl_ab, Wr_ab, Wl_ba, Wl_aa, Wr_ba, Wr_aa,
                                          wt_fb, wt_pa);
    bias_add_kernel<<<1, 128, 0, stream>>>(bl_ba, bl_aa, bias_pa);

    emb_kernel<DA><<<2048, 256, 0, stream>>>(x_a, Wemb_a, bemb_a, h_a, NA);
    emb_kernel<DB><<<2048, 256, 0, stream>>>(x_b, Wemb_b, bemb_b, h_b, NB);
    gcount_kernel<<<2, 256, 0, stream>>>(batch_a, batch_b, gcnt_a, gcnt_b);

    // ---- binned CSR build ----
    hist3_kernel<<<dim3(ECHUNKS, 3), 256, 0, stream>>>(ei_ab, ei_ba, ei_aa, binhist);
    bin_scan_kernel<<<1, 1024, 0, stream>>>(binhist, binscan, bincur, off3 + N3);
    part3_kernel<<<dim3(ECHUNKS, 3), 256, 0, stream>>>(ei_ab, ei_ba, ei_aa, bincur, binned);
    binfill3_kernel<<<dim3(NBINS_R, 3), 256, 0, stream>>>(binned, binscan, off3, csr3);

    gather3_kernel<<<dim3(2048, 3), 256, 0, stream>>>(h_a, h_b, csr3, off3, s_ab, s_ba, s_aa);

    // ---- MFMA fused GEMMs (col-split: grid.y = output half) ----
    const int lds_fb = 2 * 16384 + 256 + PG * 64 * 4;   // 35072 -> 4 blocks/CU
    const int lds_pa = 3 * 16384 + 256 + PG * 64 * 4;   // 51456 -> 3 blocks/CU
    hipFuncSetAttribute((const void*)mfma_fused<2, 0>, hipFuncAttributeMaxDynamicSharedMemorySize, lds_fb);
    hipFuncSetAttribute((const void*)mfma_fused<3, 1>, hipFuncAttributeMaxDynamicSharedMemorySize, lds_pa);

    // dst 'b': relu(s_ab@Wl_ab + h_b@Wr_ab + bl_ab) -> pool_b
    mfma_fused<2, 0><<<dim3(GT, 2), 256, lds_fb, stream>>>(s_ab, h_b, nullptr, wt_fb, bl_ab, batch_b, pool_b, NB);
    // dst 'a': relu(0.5*(s_ba@Wl_ba + s_aa@Wl_aa + h_a@(Wr_ba+Wr_aa) + bl_ba+bl_aa)) -> pool_a
    mfma_fused<3, 1><<<dim3(GT, 2), 256, lds_pa, stream>>>(s_ba, s_aa, h_a, wt_pa, bias_pa, batch_a, pool_a, NA);

    final_kernel<<<NG, 64, 0, stream>>>(pool_a, pool_b, gcnt_a, gcnt_b, Wout, bout, out);
}

// Round 7
// 538.202 us; speedup vs baseline: 18.3769x; 1.1052x over previous
//
#include <hip/hip_runtime.h>

#define NA 100000
#define NB 100000
#define NEDGE 1600000
#define HD 128
#define OUTD 16
#define NG 256
#define DA 64
#define DB 32
#define PG 8

#define BIN_SHIFT 9
#define BIN_W 512
#define NBINS_R 196              // ceil(100000/512)
#define NBINS 588                // 3 relations
#define PADBIN 10240             // padded slot per bin (E[8192], +22 sigma)
#define EPB 8192                 // edges per block in part
#define ECHUNKS 196              // ceil(NEDGE/EPB)

typedef unsigned int uint_t;
typedef unsigned short ushort_t;
typedef __bf16 bf16_t;
typedef bf16_t bf16x8 __attribute__((ext_vector_type(8)));
typedef float f32x4 __attribute__((ext_vector_type(4)));

__device__ __forceinline__ float bflo(uint_t u) {
    union { uint_t i; float f; } c; c.i = u << 16; return c.f;
}
__device__ __forceinline__ float bfhi(uint_t u) {
    union { uint_t i; float f; } c; c.i = u & 0xffff0000u; return c.f;
}
__device__ __forceinline__ uint_t f2bf(float f) {
    union { float f; uint_t i; } c; c.f = f;
    uint_t r = c.i + 0x7FFFu + ((c.i >> 16) & 1u);
    return r >> 16;
}
__device__ __forceinline__ uint_t pack2bf(float lo, float hi) {
    return f2bf(lo) | (f2bf(hi) << 16);
}

// ---------------- input embedding: h = x @ W + b  (K -> 128), bf16 out ----------------
template<int K>
__global__ void __launch_bounds__(256)
emb_kernel(const float* __restrict__ x, const float* __restrict__ W,
           const float* __restrict__ bias, ushort_t* __restrict__ h, int n)
{
    __shared__ float Ws[K * HD];
    __shared__ float bs[HD];
    for (int i = threadIdx.x; i < K * HD; i += 256) Ws[i] = W[i];
    if (threadIdx.x < HD) bs[threadIdx.x] = bias[threadIdx.x];
    __syncthreads();
    const int wid = threadIdx.x >> 6, lane = threadIdx.x & 63;
    const int c0 = 2 * lane;
    for (int row = blockIdx.x * 4 + wid; row < n; row += gridDim.x * 4) {
        const float* xr = x + (size_t)row * K;
        float a0 = bs[c0], a1 = bs[c0 + 1];
#pragma unroll 8
        for (int k = 0; k < K; ++k) {
            const float xv = xr[k];
            const float2 w = *reinterpret_cast<const float2*>(Ws + k * HD + c0);
            a0 = fmaf(xv, w.x, a0);
            a1 = fmaf(xv, w.y, a1);
        }
        *reinterpret_cast<uint_t*>(h + (size_t)row * HD + c0) = pack2bf(a0, a1);
    }
}

// ---------------- weight prep (blocks 0..39) + bias_pa (40) + gcount (41,42) ------
// layout per buffer: [half][matrix][64 rows][128 k], row = out-col (nn)
__global__ void __launch_bounds__(256)
prep_misc_kernel(const float* __restrict__ Wl_ab, const float* __restrict__ Wr_ab,
                 const float* __restrict__ Wl_ba, const float* __restrict__ Wl_aa,
                 const float* __restrict__ Wr_ba, const float* __restrict__ Wr_aa,
                 ushort_t* __restrict__ wt_fb, ushort_t* __restrict__ wt_pa,
                 const float* __restrict__ bl_ba, const float* __restrict__ bl_aa,
                 float* __restrict__ bias_pa,
                 const int* __restrict__ batch_a, const int* __restrict__ batch_b,
                 float* __restrict__ ga, float* __restrict__ gb)
{
    if (blockIdx.x >= 40) {
        if (blockIdx.x == 40) {
            if (threadIdx.x < HD) bias_pa[threadIdx.x] = bl_ba[threadIdx.x] + bl_aa[threadIdx.x];
            return;
        }
        // gcount via binary search on sorted batch
        const int g = threadIdx.x;
        const int* batch = (blockIdx.x == 42) ? batch_b : batch_a;
        float* outp = (blockIdx.x == 42) ? gb : ga;
        const int n = NA;
        int lo0 = 0, hi0 = n;
        while (lo0 < hi0) { const int mid = (lo0 + hi0) >> 1; if (batch[mid] < g) lo0 = mid + 1; else hi0 = mid; }
        int lo1 = 0, hi1 = n;
        while (lo1 < hi1) { const int mid = (lo1 + hi1) >> 1; if (batch[mid] < g + 1) lo1 = mid + 1; else hi1 = mid; }
        outp[g] = (float)(lo1 - lo0);
        return;
    }
    const int m = blockIdx.x >> 3;
    const int id = (blockIdx.x & 7) * 256 + threadIdx.x;   // 0..2047
    const int nn = id >> 4, ck = id & 15;
    const float* src = (m == 0) ? Wl_ab : (m == 1) ? Wr_ab : (m == 2) ? Wl_ba
                     : (m == 3) ? Wl_aa : Wr_ba;
    __align__(16) ushort_t tmp[8];
#pragma unroll
    for (int j = 0; j < 8; ++j) {
        const int k = ck * 8 + j;
        float v = src[k * HD + nn];
        if (m == 4) v += Wr_aa[k * HD + nn];
        tmp[j] = (ushort_t)f2bf(v);
    }
    const int cks = ck ^ (nn & 7);
    const int half = nn >> 6, nl = nn & 63;
    ushort_t* dst = (m < 2) ? (wt_fb + half * 16384 + m * 8192)
                            : (wt_pa + half * 24576 + (m - 2) * 8192);
    *reinterpret_cast<uint4*>(dst + nl * HD + cks * 8) = *reinterpret_cast<const uint4*>(tmp);
}

// ---------------- partition into PADDED per-bin slots (LDS-staged, coalesced) -----
// packed entry: (dst&511)<<17 | src   (src < 2^17)
__global__ void __launch_bounds__(256)
part3_kernel(const int* __restrict__ ei_ab, const int* __restrict__ ei_ba,
             const int* __restrict__ ei_aa, int* __restrict__ bincnt,
             uint_t* __restrict__ binned)
{
    __shared__ uint_t sorted[EPB];         // 32 KB
    __shared__ int lh[NBINS_R];
    __shared__ int lbase[NBINS_R];
    __shared__ int gbase[NBINS_R];
    __shared__ int lcur[NBINS_R];
    __shared__ int sc[256];
    const int r = blockIdx.y;
    const int* ei = (r == 0) ? ei_ab : (r == 1) ? ei_ba : ei_aa;
    const int t = threadIdx.x;
    for (int i = t; i < NBINS_R; i += 256) lh[i] = 0;
    __syncthreads();
    const int e0 = blockIdx.x * EPB;
    const int e1 = min(e0 + EPB, NEDGE);
    for (int e = e0 + t; e < e1; e += 256)
        atomicAdd(&lh[ei[NEDGE + e] >> BIN_SHIFT], 1);
    __syncthreads();
    // exclusive scan of lh (NBINS_R <= 256) + grab global slot base per bin
    {
        const int v = (t < NBINS_R) ? lh[t] : 0;
        sc[t] = v; __syncthreads();
        for (int d = 1; d < 256; d <<= 1) {
            const int x = (t >= d) ? sc[t - d] : 0;
            __syncthreads();
            sc[t] += x;
            __syncthreads();
        }
        if (t < NBINS_R) {
            const int ex = sc[t] - v;
            lbase[t] = ex; lcur[t] = ex;
            gbase[t] = v ? atomicAdd(&bincnt[r * NBINS_R + t], v) : 0;
        }
    }
    __syncthreads();
    // scatter into LDS (bin-sorted)
    for (int e = e0 + t; e < e1; e += 256) {
        const int dst = ei[NEDGE + e];
        const int src = ei[e];
        const int bin = dst >> BIN_SHIFT;
        const int pos = atomicAdd(&lcur[bin], 1);
        sorted[pos] = ((uint_t)(dst & (BIN_W - 1)) << 17) | (uint_t)src;
    }
    __syncthreads();
    // coalesced copy-out into padded bin slots
    const int wid = t >> 6, lane = t & 63;
    for (int b = wid; b < NBINS_R; b += 4) {
        const int cnt = lh[b], lb = lbase[b];
        uint_t* dst = binned + (size_t)(r * NBINS_R + b) * PADBIN + gbase[b];
        for (int k = lane; k < cnt; k += 64) dst[k] = sorted[lb + k];
    }
}

// ---------------- per-bin node offsets + counts + csr fill (one block per bin) ----
__global__ void __launch_bounds__(256)
binfill3_kernel(const uint_t* __restrict__ binned, const int* __restrict__ bincnt,
                int* __restrict__ off3, int* __restrict__ cnt3, int* __restrict__ csr3)
{
    __shared__ int hist[BIN_W];
    __shared__ int A[BIN_W];
    __shared__ int cursor[BIN_W];
    const int b = blockIdx.x;                  // bin within relation
    const int r = blockIdx.y;
    const int g = r * NBINS_R + b;
    const int start = g * PADBIN;
    const int end = start + bincnt[g];
    const int t = threadIdx.x;
    const int i0 = t, i1 = t + 256;
    hist[i0] = 0; hist[i1] = 0;
    __syncthreads();
    for (int j = start + t; j < end; j += 256)
        atomicAdd(&hist[binned[j] >> 17], 1);
    __syncthreads();
    A[i0] = hist[i0]; A[i1] = hist[i1];
    __syncthreads();
    for (int d = 1; d < BIN_W; d <<= 1) {
        const int x0 = (i0 >= d) ? A[i0 - d] : 0;
        const int x1 = (i1 >= d) ? A[i1 - d] : 0;
        __syncthreads();
        A[i0] += x0; A[i1] += x1;
        __syncthreads();
    }
    const int node0 = b * BIN_W;
#pragma unroll
    for (int q = 0; q < 2; ++q) {
        const int i = t + q * 256;
        const int ex = start + A[i] - hist[i];
        cursor[i] = ex;
        const int node = node0 + i;
        if (node < NA) { off3[r * NA + node] = ex; cnt3[r * NA + node] = hist[i]; }
    }
    __syncthreads();
    for (int j = start + t; j < end; j += 256) {
        const uint_t p = binned[j];
        const int pos = atomicAdd(&cursor[p >> 17], 1);
        csr3[pos] = (int)(p & 0x1FFFFu);
    }
}

// ---------------- gather-aggregate, half-wave-paired, 8-edge unroll ----------------
__global__ void __launch_bounds__(256)
gather3_kernel(const ushort_t* __restrict__ h_a, const ushort_t* __restrict__ h_b,
               const int* __restrict__ csr3, const int* __restrict__ off3,
               const int* __restrict__ cnt3,
               ushort_t* __restrict__ s_ab, ushort_t* __restrict__ s_ba,
               ushort_t* __restrict__ s_aa)
{
    const int r = blockIdx.y;
    const ushort_t* hsrc = (r == 1) ? h_b : h_a;
    ushort_t* s = (r == 0) ? s_ab : (r == 1) ? s_ba : s_aa;
    const int* off = off3 + r * NA;
    const int* cnt = cnt3 + r * NA;
    const int wid = threadIdx.x >> 6, lane = threadIdx.x & 63;
    const int hl = lane & 31;               // half-lane: covers cols 4*hl .. 4*hl+3
    const int nw = gridDim.x * 4;
    for (int node = blockIdx.x * 4 + wid; node < NA; node += nw) {
        const int o0 = off[node], deg = cnt[node];
        const int o1 = o0 + deg;
        float ax0 = 0.f, ax1 = 0.f, ax2 = 0.f, ax3 = 0.f;
        int j = o0;
        // 8 edges / iter: 4 independent paired loads in flight
        for (; j + 8 <= o1; j += 8) {
            const int s0 = csr3[j],     s1 = csr3[j + 1], s2 = csr3[j + 2], s3 = csr3[j + 3];
            const int s4 = csr3[j + 4], s5 = csr3[j + 5], s6 = csr3[j + 6], s7 = csr3[j + 7];
            const int sA = (lane & 32) ? s1 : s0;
            const int sB = (lane & 32) ? s3 : s2;
            const int sC = (lane & 32) ? s5 : s4;
            const int sD = (lane & 32) ? s7 : s6;
            const uint2 vA = *reinterpret_cast<const uint2*>(hsrc + (size_t)sA * HD + hl * 4);
            const uint2 vB = *reinterpret_cast<const uint2*>(hsrc + (size_t)sB * HD + hl * 4);
            const uint2 vC = *reinterpret_cast<const uint2*>(hsrc + (size_t)sC * HD + hl * 4);
            const uint2 vD = *reinterpret_cast<const uint2*>(hsrc + (size_t)sD * HD + hl * 4);
            ax0 += (bflo(vA.x) + bflo(vB.x)) + (bflo(vC.x) + bflo(vD.x));
            ax1 += (bfhi(vA.x) + bfhi(vB.x)) + (bfhi(vC.x) + bfhi(vD.x));
            ax2 += (bflo(vA.y) + bflo(vB.y)) + (bflo(vC.y) + bflo(vD.y));
            ax3 += (bfhi(vA.y) + bfhi(vB.y)) + (bfhi(vC.y) + bfhi(vD.y));
        }
        for (; j + 4 <= o1; j += 4) {
            const int s0 = csr3[j], s1 = csr3[j + 1], s2 = csr3[j + 2], s3 = csr3[j + 3];
            const int sA = (lane & 32) ? s1 : s0;
            const int sB = (lane & 32) ? s3 : s2;
            const uint2 vA = *reinterpret_cast<const uint2*>(hsrc + (size_t)sA * HD + hl * 4);
            const uint2 vB = *reinterpret_cast<const uint2*>(hsrc + (size_t)sB * HD + hl * 4);
            ax0 += bflo(vA.x) + bflo(vB.x); ax1 += bfhi(vA.x) + bfhi(vB.x);
            ax2 += bflo(vA.y) + bflo(vB.y); ax3 += bfhi(vA.y) + bfhi(vB.y);
        }
        for (; j + 2 <= o1; j += 2) {
            const int s0 = csr3[j], s1 = csr3[j + 1];
            const int sA = (lane & 32) ? s1 : s0;
            const uint2 vA = *reinterpret_cast<const uint2*>(hsrc + (size_t)sA * HD + hl * 4);
            ax0 += bflo(vA.x); ax1 += bfhi(vA.x); ax2 += bflo(vA.y); ax3 += bfhi(vA.y);
        }
        if (j < o1) {
            const int s0 = csr3[j];
            const uint2 vA = *reinterpret_cast<const uint2*>(hsrc + (size_t)s0 * HD + hl * 4);
            if (!(lane & 32)) {
                ax0 += bflo(vA.x); ax1 += bfhi(vA.x); ax2 += bflo(vA.y); ax3 += bfhi(vA.y);
            }
        }
        // cross-half reduction (lane ^ 32)
        ax0 += __shfl_xor(ax0, 32); ax1 += __shfl_xor(ax1, 32);
        ax2 += __shfl_xor(ax2, 32); ax3 += __shfl_xor(ax3, 32);
        if (!(lane & 32)) {
            const float inv = 1.0f / fmaxf((float)deg, 1.0f);
            uint2 w;
            w.x = pack2bf(ax0 * inv, ax1 * inv);
            w.y = pack2bf(ax2 * inv, ax3 * inv);
            *reinterpret_cast<uint2*>(s + (size_t)node * HD + hl * 4) = w;
        }
    }
}

// ---------------- MFMA fused GEMM body (col-split half; relu/pool epilogue) -------
template<int NSRC, int SCALE_HALF>
__device__ __forceinline__ void
mfma_body(const ushort_t* __restrict__ x0, const ushort_t* __restrict__ x1,
          const ushort_t* __restrict__ x2,
          const ushort_t* __restrict__ wts, const float* __restrict__ bias,
          const int* __restrict__ batch, float* __restrict__ outp, int n,
          char* smem)
{
    const int half = blockIdx.y;
    ushort_t* wlds   = (ushort_t*)smem;                    // NSRC*8192 bf16 (swizzled W^T half)
    float* bias_lds  = (float*)(smem + NSRC * 16384);      // 64 f32
    float* poolbuf   = bias_lds + 64;                      // PG*64 f32

    const ushort_t* wsrc = wts + (size_t)half * NSRC * 8192;
    for (int i = threadIdx.x * 8; i < NSRC * 8192; i += 256 * 8)
        *reinterpret_cast<uint4*>(wlds + i) = *reinterpret_cast<const uint4*>(wsrc + i);
    if (threadIdx.x < 64) bias_lds[threadIdx.x] = bias[half * 64 + threadIdx.x];
    for (int i = threadIdx.x; i < PG * 64; i += 256) poolbuf[i] = 0.f;
    __syncthreads();

    const int l  = threadIdx.x & 63, w = threadIdx.x >> 6;
    const int lo = l & 15, hi = l >> 4;
    const int row_base = blockIdx.x * 128 + w * 32;

    f32x4 acc[2][4];
    const f32x4 zero = {0.f, 0.f, 0.f, 0.f};
#pragma unroll
    for (int mi = 0; mi < 2; ++mi)
#pragma unroll
        for (int ni = 0; ni < 4; ++ni) acc[mi][ni] = zero;

#pragma unroll
    for (int s = 0; s < NSRC; ++s) {
        const ushort_t* xs = (s == 0) ? x0 : (s == 1) ? x1 : x2;
        bf16x8 a[2][4];
#pragma unroll
        for (int mi = 0; mi < 2; ++mi) {
            int r = row_base + mi * 16 + lo;
            r = min(r, n - 1);
            const ushort_t* xr = xs + (size_t)r * HD + hi * 8;
#pragma unroll
            for (int kk = 0; kk < 4; ++kk)
                a[mi][kk] = *reinterpret_cast<const bf16x8*>(xr + kk * 32);
        }
        const ushort_t* wb = wlds + s * 8192;
#pragma unroll
        for (int kk = 0; kk < 4; ++kk) {
#pragma unroll
            for (int ni = 0; ni < 4; ++ni) {
                const int nn = ni * 16 + lo;
                const int ck = (kk * 4 + hi) ^ (nn & 7);
                const bf16x8 b = *reinterpret_cast<const bf16x8*>(wb + nn * HD + ck * 8);
                acc[0][ni] = __builtin_amdgcn_mfma_f32_16x16x32_bf16(a[0][kk], b, acc[0][ni], 0, 0, 0);
                acc[1][ni] = __builtin_amdgcn_mfma_f32_16x16x32_bf16(a[1][kk], b, acc[1][ni], 0, 0, 0);
            }
        }
    }

    const int gmin = batch[blockIdx.x * 128];

#pragma unroll
    for (int mi = 0; mi < 2; ++mi) {
#pragma unroll
        for (int ni = 0; ni < 4; ++ni) {
            const int col_l = ni * 16 + lo;
            const int col = half * 64 + col_l;
            const float bv = bias_lds[col_l];
            const f32x4 v = acc[mi][ni];
#pragma unroll
            for (int r = 0; r < 4; ++r) {
                const int row = row_base + mi * 16 + hi * 4 + r;
                if (row < n) {
                    float val = v[r] + bv;
                    if (SCALE_HALF) val *= 0.5f;
                    val = fmaxf(val, 0.f);
                    const int g = batch[row];
                    const unsigned slot = (unsigned)(g - gmin);
                    if (slot < PG) atomicAdd(&poolbuf[slot * 64 + col_l], val);
                    else unsafeAtomicAdd(outp + (size_t)g * HD + col, val);
                }
            }
        }
    }
    __syncthreads();
    for (int i = threadIdx.x; i < PG * 64; i += 256) {
        const float v = poolbuf[i];
        if (v != 0.f) {
            const int g = gmin + (i >> 6);
            if (g < NG) unsafeAtomicAdd(outp + (size_t)g * HD + half * 64 + (i & 63), v);
        }
    }
}

// merged launcher: z=0 -> dst 'b' (NSRC=2), z=1 -> dst 'a' (NSRC=3, 0.5 scale)
__global__ void __launch_bounds__(256)
mfma_both(const ushort_t* __restrict__ s_ab, const ushort_t* __restrict__ h_b,
          const ushort_t* __restrict__ wt_fb, const float* __restrict__ bl_ab,
          const int* __restrict__ batch_b, float* __restrict__ pool_b,
          const ushort_t* __restrict__ s_ba, const ushort_t* __restrict__ s_aa,
          const ushort_t* __restrict__ h_a,
          const ushort_t* __restrict__ wt_pa, const float* __restrict__ bias_pa,
          const int* __restrict__ batch_a, float* __restrict__ pool_a)
{
    extern __shared__ char smem[];
    if (blockIdx.z == 0)
        mfma_body<2, 0>(s_ab, h_b, nullptr, wt_fb, bl_ab, batch_b, pool_b, NB, smem);
    else
        mfma_body<3, 1>(s_ba, s_aa, h_a, wt_pa, bias_pa, batch_a, pool_a, NA, smem);
}

// ---------------- head: out = (0.5*(pa/ga + pb/gb)) @ Wout + bout ----------------
__global__ void final_kernel(const float* __restrict__ pa, const float* __restrict__ pb,
                             const float* __restrict__ ga, const float* __restrict__ gb,
                             const float* __restrict__ Wout, const float* __restrict__ bout,
                             float* __restrict__ out)
{
    const int g = blockIdx.x;
    const int lane = threadIdx.x;
    const float inva = 1.0f / fmaxf(ga[g], 1.0f);
    const float invb = 1.0f / fmaxf(gb[g], 1.0f);
    if (lane < OUTD) {
        float acc = bout[lane];
        for (int k = 0; k < HD; ++k) {
            const float x = 0.5f * (pa[g * HD + k] * inva + pb[g * HD + k] * invb);
            acc = fmaf(x, Wout[k * OUTD + lane], acc);
        }
        out[g * OUTD + lane] = acc;
    }
}

extern "C" void kernel_launch(void* const* d_in, const int* in_sizes, int n_in,
                              void* d_out, int out_size, void* d_ws, size_t ws_size,
                              hipStream_t stream)
{
    const float* x_a     = (const float*)d_in[0];
    const float* x_b     = (const float*)d_in[1];
    const int*   ei_ab   = (const int*)d_in[2];
    const int*   ei_ba   = (const int*)d_in[3];
    const int*   ei_aa   = (const int*)d_in[4];
    const int*   batch_a = (const int*)d_in[5];
    const int*   batch_b = (const int*)d_in[6];
    const float* Wemb_a  = (const float*)d_in[7];
    const float* bemb_a  = (const float*)d_in[8];
    const float* Wemb_b  = (const float*)d_in[9];
    const float* bemb_b  = (const float*)d_in[10];
    const float* Wl_ab   = (const float*)d_in[11];
    const float* bl_ab   = (const float*)d_in[12];
    const float* Wr_ab   = (const float*)d_in[13];
    const float* Wl_ba   = (const float*)d_in[14];
    const float* bl_ba   = (const float*)d_in[15];
    const float* Wr_ba   = (const float*)d_in[16];
    const float* Wl_aa   = (const float*)d_in[17];
    const float* bl_aa   = (const float*)d_in[18];
    const float* Wr_aa   = (const float*)d_in[19];
    const float* Wout    = (const float*)d_in[20];
    const float* bout    = (const float*)d_in[21];
    float* out = (float*)d_out;

    // ---------------- workspace layout ----------------
    char* p = (char*)d_ws;
    ushort_t* h_a  = (ushort_t*)p; p += (size_t)NA * HD * 2;
    ushort_t* h_b  = (ushort_t*)p; p += (size_t)NB * HD * 2;
    ushort_t* s_ab = (ushort_t*)p; p += (size_t)NB * HD * 2;
    ushort_t* s_ba = (ushort_t*)p; p += (size_t)NA * HD * 2;
    ushort_t* s_aa = (ushort_t*)p; p += (size_t)NA * HD * 2;
    int* csr3   = (int*)p;  p += (size_t)NBINS * PADBIN * 4;     // 24.1 MB (padded)
    uint_t* binned = (uint_t*)p; p += (size_t)NBINS * PADBIN * 4;// 24.1 MB (padded)
    int* off3   = (int*)p;  p += (size_t)3 * NA * 4;
    int* cnt3   = (int*)p;  p += (size_t)3 * NA * 4;
    int* bincnt = (int*)p;  p += (NBINS + 4) * 4;
    float* pool_a = (float*)p; p += (size_t)NG * HD * 4;
    float* pool_b = (float*)p; p += (size_t)NG * HD * 4;
    float* gcnt_a = (float*)p; p += NG * 4;
    float* gcnt_b = (float*)p; p += NG * 4;
    ushort_t* wt_fb = (ushort_t*)p; p += 2 * 16384 * 2;
    ushort_t* wt_pa = (ushort_t*)p; p += 3 * 16384 * 2;
    float* bias_pa  = (float*)p;    p += HD * 4;

    const int GT = (NA + 127) / 128;                           // 782

    // zero pool accumulators (pool_a, pool_b contiguous) and per-bin counters
    hipMemsetAsync(pool_a, 0, (size_t)2 * NG * HD * 4, stream);
    hipMemsetAsync(bincnt, 0, (size_t)NBINS * 4, stream);

    prep_misc_kernel<<<43, 256, 0, stream>>>(Wl_ab, Wr_ab, Wl_ba, Wl_aa, Wr_ba, Wr_aa,
                                             wt_fb, wt_pa, bl_ba, bl_aa, bias_pa,
                                             batch_a, batch_b, gcnt_a, gcnt_b);

    emb_kernel<DA><<<2048, 256, 0, stream>>>(x_a, Wemb_a, bemb_a, h_a, NA);
    emb_kernel<DB><<<2048, 256, 0, stream>>>(x_b, Wemb_b, bemb_b, h_b, NB);

    // ---- padded-bin CSR build (2 kernels; no global scan needed) ----
    part3_kernel<<<dim3(ECHUNKS, 3), 256, 0, stream>>>(ei_ab, ei_ba, ei_aa, bincnt, binned);
    binfill3_kernel<<<dim3(NBINS_R, 3), 256, 0, stream>>>(binned, bincnt, off3, cnt3, csr3);

    gather3_kernel<<<dim3(2048, 3), 256, 0, stream>>>(h_a, h_b, csr3, off3, cnt3, s_ab, s_ba, s_aa);

    // ---- merged MFMA fused GEMMs (z: 0 = dst b, 1 = dst a; y = output half) ----
    const int lds_m = 3 * 16384 + 256 + PG * 64 * 4;    // 51456 -> 3 blocks/CU
    hipFuncSetAttribute((const void*)mfma_both, hipFuncAttributeMaxDynamicSharedMemorySize, lds_m);
    mfma_both<<<dim3(GT, 2, 2), 256, lds_m, stream>>>(s_ab, h_b, wt_fb, bl_ab, batch_b, pool_b,
                                                      s_ba, s_aa, h_a, wt_pa, bias_pa, batch_a, pool_a);

    final_kernel<<<NG, 64, 0, stream>>>(pool_a, pool_b, gcnt_a, gcnt_b, Wout, bout, out);
}

// Round 8
// 462.011 us; speedup vs baseline: 21.4075x; 1.1649x over previous
//
#include <hip/hip_runtime.h>

#define NA 100000
#define NB 100000
#define NEDGE 1600000
#define HD 128
#define OUTD 16
#define NG 256
#define DA 64
#define DB 32
#define PG 8

#define BIN_SHIFT 9
#define BIN_W 512
#define NBINS_R 196              // ceil(100000/512)
#define NBINS 588                // 3 relations
#define PADBIN 10240             // padded slot per bin
#define EPB 8192                 // edges per block in part
#define ECHUNKS 196              // ceil(NEDGE/EPB)

typedef unsigned int uint_t;
typedef unsigned short ushort_t;
typedef unsigned char uchar_t;
typedef __bf16 bf16_t;
typedef bf16_t bf16x8 __attribute__((ext_vector_type(8)));
typedef float f32x4 __attribute__((ext_vector_type(4)));
typedef float f32x2 __attribute__((ext_vector_type(2)));

__device__ __forceinline__ float bflo(uint_t u) {
    union { uint_t i; float f; } c; c.i = u << 16; return c.f;
}
__device__ __forceinline__ float bfhi(uint_t u) {
    union { uint_t i; float f; } c; c.i = u & 0xffff0000u; return c.f;
}
__device__ __forceinline__ uint_t f2bf(float f) {
    union { float f; uint_t i; } c; c.f = f;
    uint_t r = c.i + 0x7FFFu + ((c.i >> 16) & 1u);
    return r >> 16;
}
__device__ __forceinline__ uint_t pack2bf(float lo, float hi) {
    return f2bf(lo) | (f2bf(hi) << 16);
}

// ---------------- weight prep + bias_pa + gcount ----------------
// blocks 0..39: 5 GEMM matrices (col-half layout); 40..43: Wemb_a; 44..45: Wemb_b;
// 46: bias_pa; 47/48: gcount a/b
__global__ void __launch_bounds__(256)
prep_misc_kernel(const float* __restrict__ Wl_ab, const float* __restrict__ Wr_ab,
                 const float* __restrict__ Wl_ba, const float* __restrict__ Wl_aa,
                 const float* __restrict__ Wr_ba, const float* __restrict__ Wr_aa,
                 const float* __restrict__ Wemb_a, const float* __restrict__ Wemb_b,
                 ushort_t* __restrict__ wt_fb, ushort_t* __restrict__ wt_pa,
                 ushort_t* __restrict__ wt_ea, ushort_t* __restrict__ wt_eb,
                 const float* __restrict__ bl_ba, const float* __restrict__ bl_aa,
                 float* __restrict__ bias_pa,
                 const int* __restrict__ batch_a, const int* __restrict__ batch_b,
                 float* __restrict__ ga, float* __restrict__ gb)
{
    const int bx = blockIdx.x;
    if (bx >= 40) {
        __align__(16) ushort_t tmp[8];
        if (bx <= 43) {                          // Wemb_a, K=64
            const int id = (bx - 40) * 256 + threadIdx.x;  // 0..1023
            const int nn = id >> 3, ck = id & 7;
#pragma unroll
            for (int j = 0; j < 8; ++j) tmp[j] = (ushort_t)f2bf(Wemb_a[(ck * 8 + j) * HD + nn]);
            const int swz = ck ^ (nn & 7);
            *reinterpret_cast<uint4*>(wt_ea + nn * 64 + swz * 8) = *reinterpret_cast<const uint4*>(tmp);
            return;
        }
        if (bx <= 45) {                          // Wemb_b, K=32
            const int id = (bx - 44) * 256 + threadIdx.x;  // 0..511
            const int nn = id >> 2, ck = id & 3;
#pragma unroll
            for (int j = 0; j < 8; ++j) tmp[j] = (ushort_t)f2bf(Wemb_b[(ck * 8 + j) * HD + nn]);
            const int swz = ck ^ (nn & 3);
            *reinterpret_cast<uint4*>(wt_eb + nn * 32 + swz * 8) = *reinterpret_cast<const uint4*>(tmp);
            return;
        }
        if (bx == 46) {
            if (threadIdx.x < HD) bias_pa[threadIdx.x] = bl_ba[threadIdx.x] + bl_aa[threadIdx.x];
            return;
        }
        // gcount via binary search (batch sorted)
        const int g = threadIdx.x;
        const int* batch = (bx == 48) ? batch_b : batch_a;
        float* outp = (bx == 48) ? gb : ga;
        const int n = NA;
        int lo0 = 0, hi0 = n;
        while (lo0 < hi0) { const int mid = (lo0 + hi0) >> 1; if (batch[mid] < g) lo0 = mid + 1; else hi0 = mid; }
        int lo1 = 0, hi1 = n;
        while (lo1 < hi1) { const int mid = (lo1 + hi1) >> 1; if (batch[mid] < g + 1) lo1 = mid + 1; else hi1 = mid; }
        outp[g] = (float)(lo1 - lo0);
        return;
    }
    const int m = bx >> 3;
    const int id = (bx & 7) * 256 + threadIdx.x;   // 0..2047
    const int nn = id >> 4, ck = id & 15;
    const float* src = (m == 0) ? Wl_ab : (m == 1) ? Wr_ab : (m == 2) ? Wl_ba
                     : (m == 3) ? Wl_aa : Wr_ba;
    __align__(16) ushort_t tmp[8];
#pragma unroll
    for (int j = 0; j < 8; ++j) {
        const int k = ck * 8 + j;
        float v = src[k * HD + nn];
        if (m == 4) v += Wr_aa[k * HD + nn];
        tmp[j] = (ushort_t)f2bf(v);
    }
    const int cks = ck ^ (nn & 7);
    const int half = nn >> 6, nl = nn & 63;
    ushort_t* dst = (m < 2) ? (wt_fb + half * 16384 + m * 8192)
                            : (wt_pa + half * 24576 + (m - 2) * 8192);
    *reinterpret_cast<uint4*>(dst + nl * HD + cks * 8) = *reinterpret_cast<const uint4*>(tmp);
}

// ---------------- MFMA input embedding: h = x @ Wemb + b (K -> 128), bf16 out -----
template<int K>
__global__ void __launch_bounds__(256)
emb_mfma(const float* __restrict__ x, const ushort_t* __restrict__ wt,
         const float* __restrict__ bias, ushort_t* __restrict__ h, int n)
{
    constexpr int NCK = K / 8;
    constexpr int KST = K / 32;
    __shared__ ushort_t wlds[HD * K];
    __shared__ float bias_lds[HD];
    for (int i = threadIdx.x * 8; i < HD * K; i += 2048)
        *reinterpret_cast<uint4*>(wlds + i) = *reinterpret_cast<const uint4*>(wt + i);
    if (threadIdx.x < HD) bias_lds[threadIdx.x] = bias[threadIdx.x];
    __syncthreads();
    const int l = threadIdx.x & 63, w = threadIdx.x >> 6;
    const int lo = l & 15, hi = l >> 4;
    const int row_base = blockIdx.x * 128 + w * 32;

    f32x4 acc[2][8];
    const f32x4 zero = {0.f, 0.f, 0.f, 0.f};
#pragma unroll
    for (int mi = 0; mi < 2; ++mi)
#pragma unroll
        for (int ni = 0; ni < 8; ++ni) acc[mi][ni] = zero;

    bf16x8 a[2][KST];
#pragma unroll
    for (int mi = 0; mi < 2; ++mi) {
        int r = row_base + mi * 16 + lo;
        r = min(r, n - 1);
        const float* xr = x + (size_t)r * K + hi * 8;
#pragma unroll
        for (int kk = 0; kk < KST; ++kk) {
            const float4 f0 = *reinterpret_cast<const float4*>(xr + kk * 32);
            const float4 f1 = *reinterpret_cast<const float4*>(xr + kk * 32 + 4);
            __align__(16) ushort_t us[8];
            us[0] = (ushort_t)f2bf(f0.x); us[1] = (ushort_t)f2bf(f0.y);
            us[2] = (ushort_t)f2bf(f0.z); us[3] = (ushort_t)f2bf(f0.w);
            us[4] = (ushort_t)f2bf(f1.x); us[5] = (ushort_t)f2bf(f1.y);
            us[6] = (ushort_t)f2bf(f1.z); us[7] = (ushort_t)f2bf(f1.w);
            a[mi][kk] = *reinterpret_cast<const bf16x8*>(us);
        }
    }
#pragma unroll
    for (int kk = 0; kk < KST; ++kk) {
#pragma unroll
        for (int ni = 0; ni < 8; ++ni) {
            const int nn = ni * 16 + lo;
            const int ck = (kk * 4 + hi) ^ (nn & (NCK - 1));
            const bf16x8 b = *reinterpret_cast<const bf16x8*>(wlds + nn * K + ck * 8);
            acc[0][ni] = __builtin_amdgcn_mfma_f32_16x16x32_bf16(a[0][kk], b, acc[0][ni], 0, 0, 0);
            acc[1][ni] = __builtin_amdgcn_mfma_f32_16x16x32_bf16(a[1][kk], b, acc[1][ni], 0, 0, 0);
        }
    }
#pragma unroll
    for (int mi = 0; mi < 2; ++mi) {
#pragma unroll
        for (int ni = 0; ni < 8; ++ni) {
            const int col = ni * 16 + lo;
            const float bv = bias_lds[col];
            const f32x4 v = acc[mi][ni];
#pragma unroll
            for (int r = 0; r < 4; ++r) {
                const int row = row_base + mi * 16 + hi * 4 + r;
                if (row < n) h[(size_t)row * HD + col] = (ushort_t)f2bf(v[r] + bv);
            }
        }
    }
}

// ---------------- bf16 -> fp8 e4m3 conversion (coalesced, both tables) ------------
__global__ void __launch_bounds__(256)
conv8_kernel(const ushort_t* __restrict__ h, uchar_t* __restrict__ h8, long n8)
{
    for (long i = (long)blockIdx.x * 256 + threadIdx.x; i < n8; i += (long)gridDim.x * 256) {
        const uint4 v = *reinterpret_cast<const uint4*>(h + i * 8);
        uint_t lo = (uint_t)__builtin_amdgcn_cvt_pk_fp8_f32(bflo(v.x), bfhi(v.x), 0, false);
        lo = (uint_t)__builtin_amdgcn_cvt_pk_fp8_f32(bflo(v.y), bfhi(v.y), lo, true);
        uint_t hi = (uint_t)__builtin_amdgcn_cvt_pk_fp8_f32(bflo(v.z), bfhi(v.z), 0, false);
        hi = (uint_t)__builtin_amdgcn_cvt_pk_fp8_f32(bflo(v.w), bfhi(v.w), hi, true);
        uint2 o; o.x = lo; o.y = hi;
        *reinterpret_cast<uint2*>(h8 + i * 8) = o;
    }
}

// ---------------- partition into PADDED per-bin slots (LDS-staged, coalesced) -----
// packed entry: (dst&511)<<17 | src   (src < 2^17)
__global__ void __launch_bounds__(256)
part3_kernel(const int* __restrict__ ei_ab, const int* __restrict__ ei_ba,
             const int* __restrict__ ei_aa, int* __restrict__ bincnt,
             uint_t* __restrict__ binned)
{
    __shared__ uint_t sorted[EPB];         // 32 KB
    __shared__ int lh[NBINS_R];
    __shared__ int lbase[NBINS_R];
    __shared__ int gbase[NBINS_R];
    __shared__ int lcur[NBINS_R];
    __shared__ int sc[256];
    const int r = blockIdx.y;
    const int* ei = (r == 0) ? ei_ab : (r == 1) ? ei_ba : ei_aa;
    const int t = threadIdx.x;
    for (int i = t; i < NBINS_R; i += 256) lh[i] = 0;
    __syncthreads();
    const int e0 = blockIdx.x * EPB;
    const int e1 = min(e0 + EPB, NEDGE);
    for (int e = e0 + t; e < e1; e += 256)
        atomicAdd(&lh[ei[NEDGE + e] >> BIN_SHIFT], 1);
    __syncthreads();
    {
        const int v = (t < NBINS_R) ? lh[t] : 0;
        sc[t] = v; __syncthreads();
        for (int d = 1; d < 256; d <<= 1) {
            const int x = (t >= d) ? sc[t - d] : 0;
            __syncthreads();
            sc[t] += x;
            __syncthreads();
        }
        if (t < NBINS_R) {
            const int ex = sc[t] - v;
            lbase[t] = ex; lcur[t] = ex;
            gbase[t] = v ? atomicAdd(&bincnt[r * NBINS_R + t], v) : 0;
        }
    }
    __syncthreads();
    for (int e = e0 + t; e < e1; e += 256) {
        const int dst = ei[NEDGE + e];
        const int src = ei[e];
        const int bin = dst >> BIN_SHIFT;
        const int pos = atomicAdd(&lcur[bin], 1);
        sorted[pos] = ((uint_t)(dst & (BIN_W - 1)) << 17) | (uint_t)src;
    }
    __syncthreads();
    const int wid = t >> 6, lane = t & 63;
    for (int b = wid; b < NBINS_R; b += 4) {
        const int cnt = lh[b], lb = lbase[b];
        uint_t* dst = binned + (size_t)(r * NBINS_R + b) * PADBIN + gbase[b];
        for (int k = lane; k < cnt; k += 64) dst[k] = sorted[lb + k];
    }
}

// ---------------- per-bin node offsets + counts + csr fill (one block per bin) ----
__global__ void __launch_bounds__(256)
binfill3_kernel(const uint_t* __restrict__ binned, const int* __restrict__ bincnt,
                int* __restrict__ off3, int* __restrict__ cnt3, int* __restrict__ csr3)
{
    __shared__ int hist[BIN_W];
    __shared__ int A[BIN_W];
    __shared__ int cursor[BIN_W];
    const int b = blockIdx.x;
    const int r = blockIdx.y;
    const int g = r * NBINS_R + b;
    const int start = g * PADBIN;
    const int end = start + bincnt[g];
    const int t = threadIdx.x;
    const int i0 = t, i1 = t + 256;
    hist[i0] = 0; hist[i1] = 0;
    __syncthreads();
    for (int j = start + t; j < end; j += 256)
        atomicAdd(&hist[binned[j] >> 17], 1);
    __syncthreads();
    A[i0] = hist[i0]; A[i1] = hist[i1];
    __syncthreads();
    for (int d = 1; d < BIN_W; d <<= 1) {
        const int x0 = (i0 >= d) ? A[i0 - d] : 0;
        const int x1 = (i1 >= d) ? A[i1 - d] : 0;
        __syncthreads();
        A[i0] += x0; A[i1] += x1;
        __syncthreads();
    }
    const int node0 = b * BIN_W;
#pragma unroll
    for (int q = 0; q < 2; ++q) {
        const int i = t + q * 256;
        const int ex = start + A[i] - hist[i];
        cursor[i] = ex;
        const int node = node0 + i;
        if (node < NA) { off3[r * NA + node] = ex; cnt3[r * NA + node] = hist[i]; }
    }
    __syncthreads();
    for (int j = start + t; j < end; j += 256) {
        const uint_t p = binned[j];
        const int pos = atomicAdd(&cursor[p >> 17], 1);
        csr3[pos] = (int)(p & 0x1FFFFu);
    }
}

// ---------------- gather-aggregate from FP8 tables, half-wave-paired, 8-edge ------
__global__ void __launch_bounds__(256)
gather3_kernel(const uchar_t* __restrict__ h8_a, const uchar_t* __restrict__ h8_b,
               const int* __restrict__ csr3, const int* __restrict__ off3,
               const int* __restrict__ cnt3,
               ushort_t* __restrict__ s_ab, ushort_t* __restrict__ s_ba,
               ushort_t* __restrict__ s_aa)
{
    const int r = blockIdx.y;
    const uchar_t* hsrc = (r == 1) ? h8_b : h8_a;
    ushort_t* s = (r == 0) ? s_ab : (r == 1) ? s_ba : s_aa;
    const int* off = off3 + r * NA;
    const int* cnt = cnt3 + r * NA;
    const int wid = threadIdx.x >> 6, lane = threadIdx.x & 63;
    const int hl = lane & 31;               // half-lane: cols 4*hl .. 4*hl+3
    const int nw = gridDim.x * 4;
    for (int node = blockIdx.x * 4 + wid; node < NA; node += nw) {
        const int o0 = off[node], deg = cnt[node];
        const int o1 = o0 + deg;
        float ax0 = 0.f, ax1 = 0.f, ax2 = 0.f, ax3 = 0.f;
        int j = o0;
        for (; j + 8 <= o1; j += 8) {
            const int s0 = csr3[j],     s1 = csr3[j + 1], s2 = csr3[j + 2], s3 = csr3[j + 3];
            const int s4 = csr3[j + 4], s5 = csr3[j + 5], s6 = csr3[j + 6], s7 = csr3[j + 7];
            const int sA = (lane & 32) ? s1 : s0;
            const int sB = (lane & 32) ? s3 : s2;
            const int sC = (lane & 32) ? s5 : s4;
            const int sD = (lane & 32) ? s7 : s6;
            const uint_t vA = *reinterpret_cast<const uint_t*>(hsrc + (size_t)sA * HD + hl * 4);
            const uint_t vB = *reinterpret_cast<const uint_t*>(hsrc + (size_t)sB * HD + hl * 4);
            const uint_t vC = *reinterpret_cast<const uint_t*>(hsrc + (size_t)sC * HD + hl * 4);
            const uint_t vD = *reinterpret_cast<const uint_t*>(hsrc + (size_t)sD * HD + hl * 4);
            const f32x2 a0 = __builtin_amdgcn_cvt_pk_f32_fp8(vA, false), a1 = __builtin_amdgcn_cvt_pk_f32_fp8(vA, true);
            const f32x2 b0 = __builtin_amdgcn_cvt_pk_f32_fp8(vB, false), b1 = __builtin_amdgcn_cvt_pk_f32_fp8(vB, true);
            const f32x2 c0 = __builtin_amdgcn_cvt_pk_f32_fp8(vC, false), c1 = __builtin_amdgcn_cvt_pk_f32_fp8(vC, true);
            const f32x2 d0 = __builtin_amdgcn_cvt_pk_f32_fp8(vD, false), d1 = __builtin_amdgcn_cvt_pk_f32_fp8(vD, true);
            ax0 += (a0[0] + b0[0]) + (c0[0] + d0[0]);
            ax1 += (a0[1] + b0[1]) + (c0[1] + d0[1]);
            ax2 += (a1[0] + b1[0]) + (c1[0] + d1[0]);
            ax3 += (a1[1] + b1[1]) + (c1[1] + d1[1]);
        }
        for (; j + 2 <= o1; j += 2) {
            const int s0 = csr3[j], s1 = csr3[j + 1];
            const int sA = (lane & 32) ? s1 : s0;
            const uint_t vA = *reinterpret_cast<const uint_t*>(hsrc + (size_t)sA * HD + hl * 4);
            const f32x2 a0 = __builtin_amdgcn_cvt_pk_f32_fp8(vA, false), a1 = __builtin_amdgcn_cvt_pk_f32_fp8(vA, true);
            ax0 += a0[0]; ax1 += a0[1]; ax2 += a1[0]; ax3 += a1[1];
        }
        if (j < o1) {
            const int s0 = csr3[j];
            const uint_t vA = *reinterpret_cast<const uint_t*>(hsrc + (size_t)s0 * HD + hl * 4);
            if (!(lane & 32)) {
                const f32x2 a0 = __builtin_amdgcn_cvt_pk_f32_fp8(vA, false), a1 = __builtin_amdgcn_cvt_pk_f32_fp8(vA, true);
                ax0 += a0[0]; ax1 += a0[1]; ax2 += a1[0]; ax3 += a1[1];
            }
        }
        ax0 += __shfl_xor(ax0, 32); ax1 += __shfl_xor(ax1, 32);
        ax2 += __shfl_xor(ax2, 32); ax3 += __shfl_xor(ax3, 32);
        if (!(lane & 32)) {
            const float inv = 1.0f / fmaxf((float)deg, 1.0f);
            uint2 wv;
            wv.x = pack2bf(ax0 * inv, ax1 * inv);
            wv.y = pack2bf(ax2 * inv, ax3 * inv);
            *reinterpret_cast<uint2*>(s + (size_t)node * HD + hl * 4) = wv;
        }
    }
}

// ---------------- MFMA fused GEMM body: A-regs once, loop both output halves ------
template<int NSRC, int SCALE_HALF>
__device__ __forceinline__ void
mfma_body(const ushort_t* __restrict__ x0, const ushort_t* __restrict__ x1,
          const ushort_t* __restrict__ x2,
          const ushort_t* __restrict__ wts, const float* __restrict__ bias,
          const int* __restrict__ batch, float* __restrict__ outp, int n,
          char* smem)
{
    ushort_t* wlds   = (ushort_t*)smem;                    // NSRC*8192 bf16 (one half's swizzled W^T)
    float* bias_lds  = (float*)(smem + NSRC * 16384);      // 128 f32
    float* poolbuf   = bias_lds + HD;                      // PG*64 f32

    const int l  = threadIdx.x & 63, w = threadIdx.x >> 6;
    const int lo = l & 15, hi = l >> 4;
    const int row_base = blockIdx.x * 128 + w * 32;

    // load all A fragments once (kept in registers across both halves)
    bf16x8 a[NSRC][2][4];
#pragma unroll
    for (int s = 0; s < NSRC; ++s) {
        const ushort_t* xs = (s == 0) ? x0 : (s == 1) ? x1 : x2;
#pragma unroll
        for (int mi = 0; mi < 2; ++mi) {
            int r = row_base + mi * 16 + lo;
            r = min(r, n - 1);
            const ushort_t* xr = xs + (size_t)r * HD + hi * 8;
#pragma unroll
            for (int kk = 0; kk < 4; ++kk)
                a[s][mi][kk] = *reinterpret_cast<const bf16x8*>(xr + kk * 32);
        }
    }
    if (threadIdx.x < HD) bias_lds[threadIdx.x] = bias[threadIdx.x];
    const int gmin = batch[blockIdx.x * 128];

    for (int half = 0; half < 2; ++half) {
        __syncthreads();      // previous compute / poolbuf flush done
        const ushort_t* wsrc = wts + (size_t)half * NSRC * 8192;
        for (int i = threadIdx.x * 8; i < NSRC * 8192; i += 256 * 8)
            *reinterpret_cast<uint4*>(wlds + i) = *reinterpret_cast<const uint4*>(wsrc + i);
        for (int i = threadIdx.x; i < PG * 64; i += 256) poolbuf[i] = 0.f;
        __syncthreads();

        f32x4 acc[2][4];
        const f32x4 zero = {0.f, 0.f, 0.f, 0.f};
#pragma unroll
        for (int mi = 0; mi < 2; ++mi)
#pragma unroll
            for (int ni = 0; ni < 4; ++ni) acc[mi][ni] = zero;

#pragma unroll
        for (int s = 0; s < NSRC; ++s) {
            const ushort_t* wb = wlds + s * 8192;
#pragma unroll
            for (int kk = 0; kk < 4; ++kk) {
#pragma unroll
                for (int ni = 0; ni < 4; ++ni) {
                    const int nn = ni * 16 + lo;
                    const int ck = (kk * 4 + hi) ^ (nn & 7);
                    const bf16x8 b = *reinterpret_cast<const bf16x8*>(wb + nn * HD + ck * 8);
                    acc[0][ni] = __builtin_amdgcn_mfma_f32_16x16x32_bf16(a[s][0][kk], b, acc[0][ni], 0, 0, 0);
                    acc[1][ni] = __builtin_amdgcn_mfma_f32_16x16x32_bf16(a[s][1][kk], b, acc[1][ni], 0, 0, 0);
                }
            }
        }

#pragma unroll
        for (int mi = 0; mi < 2; ++mi) {
#pragma unroll
            for (int ni = 0; ni < 4; ++ni) {
                const int col_l = ni * 16 + lo;
                const int col = half * 64 + col_l;
                const float bv = bias_lds[col];
                const f32x4 v = acc[mi][ni];
#pragma unroll
                for (int r = 0; r < 4; ++r) {
                    const int row = row_base + mi * 16 + hi * 4 + r;
                    if (row < n) {
                        float val = v[r] + bv;
                        if (SCALE_HALF) val *= 0.5f;
                        val = fmaxf(val, 0.f);
                        const int g = batch[row];
                        const unsigned slot = (unsigned)(g - gmin);
                        if (slot < PG) atomicAdd(&poolbuf[slot * 64 + col_l], val);
                        else unsafeAtomicAdd(outp + (size_t)g * HD + col, val);
                    }
                }
            }
        }
        __syncthreads();
        for (int i = threadIdx.x; i < PG * 64; i += 256) {
            const float v = poolbuf[i];
            if (v != 0.f) {
                const int g = gmin + (i >> 6);
                if (g < NG) unsafeAtomicAdd(outp + (size_t)g * HD + half * 64 + (i & 63), v);
            }
        }
    }
}

// merged launcher: y=0 -> dst 'b' (NSRC=2), y=1 -> dst 'a' (NSRC=3, 0.5 scale)
__global__ void __launch_bounds__(256)
mfma_both(const ushort_t* __restrict__ s_ab, const ushort_t* __restrict__ h_b,
          const ushort_t* __restrict__ wt_fb, const float* __restrict__ bl_ab,
          const int* __restrict__ batch_b, float* __restrict__ pool_b,
          const ushort_t* __restrict__ s_ba, const ushort_t* __restrict__ s_aa,
          const ushort_t* __restrict__ h_a,
          const ushort_t* __restrict__ wt_pa, const float* __restrict__ bias_pa,
          const int* __restrict__ batch_a, float* __restrict__ pool_a)
{
    extern __shared__ char smem[];
    if (blockIdx.y == 0)
        mfma_body<2, 0>(s_ab, h_b, nullptr, wt_fb, bl_ab, batch_b, pool_b, NB, smem);
    else
        mfma_body<3, 1>(s_ba, s_aa, h_a, wt_pa, bias_pa, batch_a, pool_a, NA, smem);
}

// ---------------- head: out = (0.5*(pa/ga + pb/gb)) @ Wout + bout ----------------
__global__ void final_kernel(const float* __restrict__ pa, const float* __restrict__ pb,
                             const float* __restrict__ ga, const float* __restrict__ gb,
                             const float* __restrict__ Wout, const float* __restrict__ bout,
                             float* __restrict__ out)
{
    const int g = blockIdx.x;
    const int lane = threadIdx.x;
    const float inva = 1.0f / fmaxf(ga[g], 1.0f);
    const float invb = 1.0f / fmaxf(gb[g], 1.0f);
    if (lane < OUTD) {
        float acc = bout[lane];
        for (int k = 0; k < HD; ++k) {
            const float x = 0.5f * (pa[g * HD + k] * inva + pb[g * HD + k] * invb);
            acc = fmaf(x, Wout[k * OUTD + lane], acc);
        }
        out[g * OUTD + lane] = acc;
    }
}

extern "C" void kernel_launch(void* const* d_in, const int* in_sizes, int n_in,
                              void* d_out, int out_size, void* d_ws, size_t ws_size,
                              hipStream_t stream)
{
    const float* x_a     = (const float*)d_in[0];
    const float* x_b     = (const float*)d_in[1];
    const int*   ei_ab   = (const int*)d_in[2];
    const int*   ei_ba   = (const int*)d_in[3];
    const int*   ei_aa   = (const int*)d_in[4];
    const int*   batch_a = (const int*)d_in[5];
    const int*   batch_b = (const int*)d_in[6];
    const float* Wemb_a  = (const float*)d_in[7];
    const float* bemb_a  = (const float*)d_in[8];
    const float* Wemb_b  = (const float*)d_in[9];
    const float* bemb_b  = (const float*)d_in[10];
    const float* Wl_ab   = (const float*)d_in[11];
    const float* bl_ab   = (const float*)d_in[12];
    const float* Wr_ab   = (const float*)d_in[13];
    const float* Wl_ba   = (const float*)d_in[14];
    const float* bl_ba   = (const float*)d_in[15];
    const float* Wr_ba   = (const float*)d_in[16];
    const float* Wl_aa   = (const float*)d_in[17];
    const float* bl_aa   = (const float*)d_in[18];
    const float* Wr_aa   = (const float*)d_in[19];
    const float* Wout    = (const float*)d_in[20];
    const float* bout    = (const float*)d_in[21];
    float* out = (float*)d_out;

    // ---------------- workspace layout ----------------
    char* p = (char*)d_ws;
    ushort_t* h_a  = (ushort_t*)p; p += (size_t)NA * HD * 2;     // h_a, h_b contiguous
    ushort_t* h_b  = (ushort_t*)p; p += (size_t)NB * HD * 2;
    ushort_t* s_ab = (ushort_t*)p; p += (size_t)NB * HD * 2;
    ushort_t* s_ba = (ushort_t*)p; p += (size_t)NA * HD * 2;
    ushort_t* s_aa = (ushort_t*)p; p += (size_t)NA * HD * 2;
    uchar_t* h8_a  = (uchar_t*)p;  p += (size_t)NA * HD;         // h8_a, h8_b contiguous
    uchar_t* h8_b  = (uchar_t*)p;  p += (size_t)NB * HD;
    int* csr3   = (int*)p;  p += (size_t)NBINS * PADBIN * 4;     // 24.1 MB (padded)
    uint_t* binned = (uint_t*)p; p += (size_t)NBINS * PADBIN * 4;// 24.1 MB (padded)
    int* off3   = (int*)p;  p += (size_t)3 * NA * 4;
    int* cnt3   = (int*)p;  p += (size_t)3 * NA * 4;
    int* bincnt = (int*)p;  p += (NBINS + 4) * 4;
    float* pool_a = (float*)p; p += (size_t)NG * HD * 4;
    float* pool_b = (float*)p; p += (size_t)NG * HD * 4;
    float* gcnt_a = (float*)p; p += NG * 4;
    float* gcnt_b = (float*)p; p += NG * 4;
    ushort_t* wt_fb = (ushort_t*)p; p += 2 * 16384 * 2;
    ushort_t* wt_pa = (ushort_t*)p; p += 3 * 16384 * 2;
    ushort_t* wt_ea = (ushort_t*)p; p += 64 * HD * 2;
    ushort_t* wt_eb = (ushort_t*)p; p += 32 * HD * 2;
    float* bias_pa  = (float*)p;    p += HD * 4;

    const int GT = (NA + 127) / 128;                           // 782

    hipMemsetAsync(pool_a, 0, (size_t)2 * NG * HD * 4, stream);
    hipMemsetAsync(bincnt, 0, (size_t)NBINS * 4, stream);

    prep_misc_kernel<<<49, 256, 0, stream>>>(Wl_ab, Wr_ab, Wl_ba, Wl_aa, Wr_ba, Wr_aa,
                                             Wemb_a, Wemb_b, wt_fb, wt_pa, wt_ea, wt_eb,
                                             bl_ba, bl_aa, bias_pa,
                                             batch_a, batch_b, gcnt_a, gcnt_b);

    emb_mfma<DA><<<GT, 256, 0, stream>>>(x_a, wt_ea, bemb_a, h_a, NA);
    emb_mfma<DB><<<GT, 256, 0, stream>>>(x_b, wt_eb, bemb_b, h_b, NB);
    conv8_kernel<<<2048, 256, 0, stream>>>(h_a, h8_a, (long)(NA + NB) * HD / 8);

    // ---- padded-bin CSR build ----
    part3_kernel<<<dim3(ECHUNKS, 3), 256, 0, stream>>>(ei_ab, ei_ba, ei_aa, bincnt, binned);
    binfill3_kernel<<<dim3(NBINS_R, 3), 256, 0, stream>>>(binned, bincnt, off3, cnt3, csr3);

    gather3_kernel<<<dim3(2048, 3), 256, 0, stream>>>(h8_a, h8_b, csr3, off3, cnt3, s_ab, s_ba, s_aa);

    // ---- merged MFMA fused GEMMs (y: 0 = dst b, 1 = dst a; both halves internal) ----
    const int lds_m = 3 * 16384 + 512 + PG * 64 * 4;    // 51712 -> 3 blocks/CU
    hipFuncSetAttribute((const void*)mfma_both, hipFuncAttributeMaxDynamicSharedMemorySize, lds_m);
    mfma_both<<<dim3(GT, 2), 256, lds_m, stream>>>(s_ab, h_b, wt_fb, bl_ab, batch_b, pool_b,
                                                   s_ba, s_aa, h_a, wt_pa, bias_pa, batch_a, pool_a);

    final_kernel<<<NG, 64, 0, stream>>>(pool_a, pool_b, gcnt_a, gcnt_b, Wout, bout, out);
}